// Round 6
// baseline (559.657 us; speedup 1.0000x reference)
//
#include <hip/hip_runtime.h>
#include <hip/hip_bf16.h>

typedef __attribute__((ext_vector_type(8)))  short s8v;   // 8 bf16
typedef __attribute__((ext_vector_type(4)))  float f4v;   // 16x16 C/D
typedef _Float16 h4 __attribute__((ext_vector_type(4)));  // 4 f16
typedef _Float16 h8 __attribute__((ext_vector_type(8)));  // 8 f16
typedef __attribute__((ext_vector_type(4))) unsigned short u4v;

constexpr int NCn  = 128;
constexpr int DDn  = 65536;
constexpr int XP   = 264;             // padded LDS row (bf16 elems)
constexpr float EPSf = 1.1920929e-07f;

__device__ __forceinline__ float sigm(float x){ return 1.0f/(1.0f + expf(-x)); }
__device__ __forceinline__ float silu_(float x){ return x * sigm(x); }
__device__ __forceinline__ float dsilu_(float x){ float s = sigm(x); return s*(1.0f + x*(1.0f - s)); }

__device__ __forceinline__ unsigned short f2b(float x){
    __hip_bfloat16 b = __float2bfloat16(x);
    unsigned short u; __builtin_memcpy(&u, &b, 2); return u;
}
__device__ __forceinline__ float b2f(unsigned short u){
    __hip_bfloat16 b; __builtin_memcpy(&b, &u, 2); return __bfloat162float(b);
}
__device__ __forceinline__ h4 ldh4(const unsigned short* p){
    h4 r; __builtin_memcpy(&r, p, 8); return r;
}

__device__ __forceinline__ float block_sum(float v, float* red){   // 256 thr
    #pragma unroll
    for (int off = 32; off; off >>= 1) v += __shfl_down(v, off, 64);
    if ((threadIdx.x & 63) == 0) red[threadIdx.x >> 6] = v;
    __syncthreads();
    float r = red[0] + red[1] + red[2] + red[3];
    __syncthreads();
    return r;
}

// ---- merged weight prep: z 0..5 tiled transpose fp32->bf16, z 6..8 cast-copy ----
__global__ __launch_bounds__(256) void ktw(const float* __restrict__ Wq,
        const float* __restrict__ Wkv, const float* __restrict__ W0,
        const float* __restrict__ W1, const float* __restrict__ W2,
        const float* __restrict__ W3, unsigned short* __restrict__ WTb,
        unsigned short* __restrict__ WqTb, unsigned short* __restrict__ WkvTb,
        unsigned short* __restrict__ Wb){
    int z = blockIdx.z;
    if (z >= 6){
        const float* S = (z==6)?W1:(z==7)?W2:W3;
        size_t idx = (((size_t)blockIdx.y*8 + blockIdx.x)*256 + threadIdx.x)*2;
        float2 v = *(const float2*)(S + idx);
        ushort2 u; u.x = f2b(v.x); u.y = f2b(v.y);
        *(ushort2*)(Wb + (size_t)(z-6)*DDn + idx) = u;
        return;
    }
    __shared__ float tl[32][33];
    if (z != 5 && blockIdx.y >= 8) return;
    const float* S; unsigned short* T; int C;
    if (z < 4){ S = (z==0)?W0:(z==1)?W1:(z==2)?W2:W3; T = WTb + (size_t)z*DDn; C = 256; }
    else if (z == 4){ S = Wq; T = WqTb; C = 256; }
    else { S = Wkv; T = WkvTb; C = 512; }
    int k0 = blockIdx.x*32, j0 = blockIdx.y*32;
    int tx = threadIdx.x & 31, ty = threadIdx.x >> 5;
    #pragma unroll
    for (int p = 0; p < 4; ++p)
        tl[ty + 8*p][tx] = S[(size_t)(k0 + ty + 8*p)*C + j0 + tx];
    __syncthreads();
    #pragma unroll
    for (int p = 0; p < 4; ++p)
        T[(size_t)(j0 + ty + 8*p)*256 + k0 + tx] = f2b(tl[tx][ty + 8*p]);
}

// ---- per-token norm, scatter sn + shifted rn ----
__global__ __launch_bounds__(256) void knorm(const float* __restrict__ seq,
        const float* __restrict__ wsn, const float* __restrict__ wrn,
        unsigned short* __restrict__ snb, unsigned short* __restrict__ rnb){
    __shared__ float red[4];
    int t = blockIdx.x, d = threadIdx.x;
    int b = t >> 10, tl = t & 1023, g = t >> 4, c = tl & 15;
    float x = seq[(size_t)t*256 + d];
    float ss = block_sum(x*x, red);
    float xr = x * rsqrtf(ss*(1.f/256.f) + EPSf);
    snb[(size_t)g*4096 + c*256 + d] = f2b(xr*wsn[d]);
    if (tl >= 15){
        int tl2 = tl - 15, g2 = b*64 + (tl2 >> 4), c2 = tl2 & 15;
        rnb[(size_t)g2*4096 + c2*256 + d] = f2b(xr*wrn[d]);
    }
    if (tl >= 1009)
        rnb[(size_t)g*4096 + c*256 + d] = 0;
}

// ---- fwd + bwd dgrads + fused gates, one block per group, 16 waves ----
// writes Xb bf16 [l][g][c][d], XT f16 [l][g][d][c], GT f16 [l][g][d][c]
__global__ __launch_bounds__(1024, 1) void kfb(const unsigned short* __restrict__ snb,
        const unsigned short* __restrict__ WkvTb, const unsigned short* __restrict__ WTb,
        const unsigned short* __restrict__ Wb,
        const float* __restrict__ wa, const float* __restrict__ wm,
        const float* __restrict__ wdk,
        float* __restrict__ momg, float* __restrict__ decg,
        unsigned short* __restrict__ Xb, unsigned short* __restrict__ XT,
        unsigned short* __restrict__ GT){
    __shared__ unsigned short xl[4][16][XP];
    __shared__ unsigned short Gs[16][XP];
    __shared__ float red3[16][4];
    int tid = threadIdx.x, w = tid >> 6, lane = tid & 63;
    int m16 = lane & 15, q16 = lane >> 4;
    int g = blockIdx.x;
    int n0 = w*16;

    float sc;
    {   // fused gates: one reduction pass, one barrier
        int d2 = tid & 255, qt = tid >> 8;
        float a = 0.f;
        #pragma unroll
        for (int c = 0; c < 4; ++c)
            a += b2f(snb[(size_t)g*4096 + (qt*4 + c)*256 + d2]);
        float cm = a * (1.f/16.f);
        float s0 = cm*wa[d2], s1 = cm*wm[d2], s2 = cm*wdk[d2];
        #pragma unroll
        for (int off = 32; off; off >>= 1){
            s0 += __shfl_down(s0, off, 64);
            s1 += __shfl_down(s1, off, 64);
            s2 += __shfl_down(s2, off, 64);
        }
        if (lane == 0){ red3[w][0] = s0; red3[w][1] = s1; red3[w][2] = s2; }
        __syncthreads();
        float da = 0.f, dm = 0.f, dc = 0.f;
        #pragma unroll
        for (int i = 0; i < 16; ++i){
            da += red3[i][0]; dm += red3[i][1]; dc += red3[i][2];
        }
        sc = -2.f * sigm(da) * (1.f/256.f);
        if (tid == 0){ momg[g] = sigm(dm); decg[g] = sigm(dc); }
    }

    s8v af[8];
    const unsigned short* arow = snb + (size_t)g*4096 + m16*256 + q16*8;
    #pragma unroll
    for (int i = 0; i < 8; ++i) af[i] = *(const s8v*)(arow + i*32);

    f4v vacc;
    {
        f4v ka = {0.f,0.f,0.f,0.f}, va = {0.f,0.f,0.f,0.f};
        const unsigned short* brK = WkvTb + (size_t)(n0 + m16)*256 + q16*8;
        const unsigned short* brV = WkvTb + (size_t)(256 + n0 + m16)*256 + q16*8;
        #pragma unroll
        for (int i = 0; i < 8; ++i){
            s8v bK = *(const s8v*)(brK + i*32);
            s8v bV = *(const s8v*)(brV + i*32);
            ka = __builtin_amdgcn_mfma_f32_16x16x32_bf16(af[i], bK, ka, 0, 0, 0);
            va = __builtin_amdgcn_mfma_f32_16x16x32_bf16(af[i], bV, va, 0, 0, 0);
        }
        vacc = va;
        #pragma unroll
        for (int r = 0; r < 4; ++r) xl[0][4*q16 + r][n0 + m16] = f2b(ka[r]);
    }

    f4v hreg[3];
    for (int l = 0; l < 3; ++l){
        __syncthreads();
        s8v xa[8];
        #pragma unroll
        for (int i = 0; i < 8; ++i)
            xa[i] = *(const s8v*)(&xl[l][m16][q16*8 + i*32]);
        const unsigned short* Wt = WTb + (size_t)l*DDn;
        f4v acc = {0.f,0.f,0.f,0.f};
        const unsigned short* br = Wt + (size_t)(n0 + m16)*256 + q16*8;
        #pragma unroll
        for (int i = 0; i < 8; ++i){
            s8v b = *(const s8v*)(br + i*32);
            acc = __builtin_amdgcn_mfma_f32_16x16x32_bf16(xa[i], b, acc, 0, 0, 0);
        }
        hreg[l] = acc;
        #pragma unroll
        for (int r = 0; r < 4; ++r)
            xl[l+1][4*q16 + r][n0 + m16] = f2b(silu_(acc[r]));
    }
    __syncthreads();

    {   // dump layer inputs Xb[l][g][c][d] bf16 (direct copy from xl)
        int c = tid >> 6, d4 = (tid & 63)*4;
        #pragma unroll
        for (int l = 0; l < 4; ++l)
            *(u4v*)(Xb + (((size_t)l*128 + g)*16 + c)*256 + d4) =
                *(const u4v*)(&xl[l][c][d4]);
    }
    {   // dump XT f16 [l][g][d][c]
        int d = tid & 255, qt = tid >> 8;
        #pragma unroll
        for (int l = 0; l < 4; ++l){
            h4 v;
            #pragma unroll
            for (int j = 0; j < 4; ++j)
                v[j] = (_Float16)b2f(xl[l][qt*4 + j][d]);
            *(h4*)(XT + (((size_t)l*128 + g)*256 + d)*16 + qt*4) = v;
        }
    }

    {   // layer 3 (pred) -> Gs
        s8v xa[8];
        #pragma unroll
        for (int i = 0; i < 8; ++i)
            xa[i] = *(const s8v*)(&xl[3][m16][q16*8 + i*32]);
        const unsigned short* Wt = WTb + (size_t)3*DDn;
        f4v acc = {0.f,0.f,0.f,0.f};
        const unsigned short* br = Wt + (size_t)(n0 + m16)*256 + q16*8;
        #pragma unroll
        for (int i = 0; i < 8; ++i){
            s8v b = *(const s8v*)(br + i*32);
            acc = __builtin_amdgcn_mfma_f32_16x16x32_bf16(xa[i], b, acc, 0, 0, 0);
        }
        #pragma unroll
        for (int r = 0; r < 4; ++r)
            Gs[4*q16 + r][n0 + m16] = f2b(sc * (acc[r] - vacc[r]));
    }
    __syncthreads();
    {   // write f16 GT[3][g][d][c]
        int d = tid & 255, qt = tid >> 8;
        h4 v;
        #pragma unroll
        for (int j = 0; j < 4; ++j)
            v[j] = (_Float16)b2f(Gs[qt*4 + j][d]);
        *(h4*)(GT + (((size_t)3*128 + g)*256 + d)*16 + qt*4) = v;
    }

    for (int l = 3; l >= 1; --l){
        s8v gfa[8];
        #pragma unroll
        for (int i = 0; i < 8; ++i)
            gfa[i] = *(const s8v*)(&Gs[m16][q16*8 + i*32]);
        const unsigned short* Wr = Wb + (size_t)(l-1)*DDn;
        f4v acc = {0.f,0.f,0.f,0.f};
        const unsigned short* br = Wr + (size_t)(n0 + m16)*256 + q16*8;
        #pragma unroll
        for (int i = 0; i < 8; ++i){
            s8v b = *(const s8v*)(br + i*32);
            acc = __builtin_amdgcn_mfma_f32_16x16x32_bf16(gfa[i], b, acc, 0, 0, 0);
        }
        f4v gn;
        #pragma unroll
        for (int r = 0; r < 4; ++r)
            gn[r] = acc[r] * dsilu_(hreg[l-1][r]);
        __syncthreads();
        #pragma unroll
        for (int r = 0; r < 4; ++r)
            Gs[4*q16 + r][n0 + m16] = f2b(gn[r]);
        __syncthreads();
        {
            int d = tid & 255, qt = tid >> 8;
            h4 v;
            #pragma unroll
            for (int j = 0; j < 4; ++j)
                v[j] = (_Float16)b2f(Gs[qt*4 + j][d]);
            *(h4*)(GT + (((size_t)(l-1)*128 + g)*256 + d)*16 + qt*4) = v;
        }
    }
}

// ---- coefficients: cf(g,n), mp(g,n), and per-g segment scalars A_g,B_g,PImo_g ----
__global__ __launch_bounds__(64) void kcoef(const float* __restrict__ momg,
        const float* __restrict__ decg, float* __restrict__ coefb,
        float* __restrict__ mpb, float* __restrict__ apg,
        float* __restrict__ bpg, float* __restrict__ mpg){
    int b = blockIdx.x, n = threadIdx.x;
    float M = 0.f, cf = 0.f;
    for (int gg = 0; gg < 64; ++gg){
        float mo = momg[b*64 + gg], de = 1.f - decg[b*64 + gg];
        if (gg == n){ M = 1.f; cf = 1.f; }
        else if (gg > n){ M *= mo; cf = de*cf + M; }
        coefb[((size_t)b*64 + gg)*64 + n] = cf;
        mpb  [((size_t)b*64 + gg)*64 + n] = M;
    }
    int ss0 = n & ~7;
    float a = 1.f, B = 0.f, pm = 1.f;
    for (int j = ss0; j <= n; ++j){
        float mo = momg[b*64 + j], de = 1.f - decg[b*64 + j];
        pm *= mo; B = de*B + pm; a *= de;
    }
    apg[b*64 + n] = a; bpg[b*64 + n] = B; mpg[b*64 + n] = pm;
}

// ---- fused segment partials + scan -> bf16 checkpoints Ucp/Mcp ----
// grid (4 rowtiles, 8 bl=b*4+l), 256 thr; scan state in registers (static idx)
__global__ __launch_bounds__(256, 1) void kck(const unsigned short* __restrict__ XT,
        const unsigned short* __restrict__ GT, const float* __restrict__ coefb,
        const float* __restrict__ mpb, const float* __restrict__ apg,
        const float* __restrict__ bpg, const float* __restrict__ mpg,
        unsigned short* __restrict__ ucpb, unsigned short* __restrict__ mcpb){
    int lane = threadIdx.x & 63, w = threadIdx.x >> 6;
    int m16 = lane & 15, q16 = lane >> 4;
    int rt = blockIdx.x, bl = blockIdx.y;
    int b = bl >> 2, l = bl & 3;
    int d2 = rt*64 + w*16 + m16;
    float us[16][4], ms[16][4];
    #pragma unroll
    for (int ct = 0; ct < 16; ++ct)
        #pragma unroll
        for (int r = 0; r < 4; ++r){ us[ct][r] = 0.f; ms[ct][r] = 0.f; }

    for (int s = 0; s < 7; ++s){
        int e = b*64 + s*8 + 7;
        float av = apg[e], bv = bpg[e], mv = mpg[e];
        const float* cfr = coefb + (size_t)e*64;
        const float* mpr = mpb   + (size_t)e*64;
        h4 au[8], am[8];
        #pragma unroll
        for (int n = 0; n < 8; ++n){
            int cid = s*8 + n;
            h4 a = ldh4(GT + (((size_t)l*128 + b*64 + cid)*256 + d2)*16 + q16*4);
            _Float16 cfh = (_Float16)cfr[cid];
            _Float16 mph = (_Float16)mpr[cid];
            au[n] = a*cfh; am[n] = a*mph;
        }
        #pragma unroll
        for (int ct = 0; ct < 16; ++ct){
            int d1 = ct*16 + m16;
            f4v acu = {0.f,0.f,0.f,0.f}, acm = {0.f,0.f,0.f,0.f};
            #pragma unroll
            for (int n = 0; n < 8; ++n){
                int cid = s*8 + n;
                h4 xb = ldh4(XT + (((size_t)l*128 + b*64 + cid)*256 + d1)*16 + q16*4);
                acu = __builtin_amdgcn_mfma_f32_16x16x16f16(au[n], xb, acu, 0, 0, 0);
                acm = __builtin_amdgcn_mfma_f32_16x16x16f16(am[n], xb, acm, 0, 0, 0);
            }
            size_t ob = (((size_t)bl*7 + s)*256 + (size_t)(rt*64 + w*16))*256 + d1;
            #pragma unroll
            for (int r = 0; r < 4; ++r){
                float un = av*us[ct][r] + bv*ms[ct][r] + acu[r];
                float mn = mv*ms[ct][r] + acm[r];
                us[ct][r] = un; ms[ct][r] = mn;
                ucpb[ob + (size_t)(4*q16 + r)*256] = f2b(un);
                mcpb[ob + (size_t)(4*q16 + r)*256] = f2b(mn);
            }
        }
    }
}

// ---- retrieval: q-proj + 4 layers {x@(W + A*Ucp + B*Mcp) + <=8 local chunks} ----
// one block per group; 16 waves; 1 barrier/layer; scores redundant per-wave in regs
__global__ __launch_bounds__(1024, 1) void kretr(const unsigned short* __restrict__ rnb,
        const unsigned short* __restrict__ WqTb, const unsigned short* __restrict__ WTb,
        const unsigned short* __restrict__ ucpb, const unsigned short* __restrict__ mcpb,
        const unsigned short* __restrict__ Xb, const unsigned short* __restrict__ GT,
        const float* __restrict__ coefb, const float* __restrict__ apg,
        const float* __restrict__ bpg, const float* __restrict__ wpost,
        float* __restrict__ out){
    __shared__ unsigned short xc[2][16][XP];
    __shared__ float red[16][16];
    __shared__ float rs[16];
    int tid = threadIdx.x, w = tid >> 6, lane = tid & 63;
    int m16 = lane & 15, q16 = lane >> 4;
    // XCD swizzle: co-locate the 8 blocks sharing a (b,seg) checkpoint on one XCD
    int B = blockIdx.x;
    int g = (((B & 7)*2) + ((B >> 3) & 1))*8 + (B >> 4);
    int b = g >> 6, nl = g & 63;
    int seg = nl >> 3, sbase = seg*8;
    int segm1 = seg ? seg - 1 : 0;
    float uaf = seg ? apg[g] : 0.f;
    float ubf = seg ? bpg[g] : 0.f;
    int n0 = w*16;

    {   // q-projection
        s8v a[8];
        const unsigned short* ar = rnb + (size_t)g*4096 + m16*256 + q16*8;
        #pragma unroll
        for (int i = 0; i < 8; ++i) a[i] = *(const s8v*)(ar + i*32);
        f4v acc = {0.f,0.f,0.f,0.f};
        const unsigned short* br = WqTb + (size_t)(n0 + m16)*256 + q16*8;
        #pragma unroll
        for (int i = 0; i < 8; ++i){
            s8v bb = *(const s8v*)(br + i*32);
            acc = __builtin_amdgcn_mfma_f32_16x16x32_bf16(a[i], bb, acc, 0, 0, 0);
        }
        #pragma unroll
        for (int r = 0; r < 4; ++r) xc[0][4*q16 + r][n0 + m16] = f2b(acc[r]);
    }
    __syncthreads();

    const float* cfp = coefb + (size_t)g*64 + sbase;   // zeros past nl (kcoef init)
    f4v hacc;
    for (int l = 0; l < 4; ++l){
        s8v xa[8];
        #pragma unroll
        for (int i = 0; i < 8; ++i)
            xa[i] = *(const s8v*)(&xc[l & 1][m16][q16*8 + i*32]);
        // dense: x @ (W + A*Ucp + B*Mcp)  (uniform path; seg==0 scales by 0)
        {
            const unsigned short* br = WTb + (size_t)l*DDn + (size_t)(n0 + m16)*256 + q16*8;
            size_t cko = ((size_t)(b*4 + l)*7 + segm1)*65536 + (size_t)(n0 + m16)*256 + q16*8;
            const unsigned short* bu = ucpb + cko;
            const unsigned short* bm = mcpb + cko;
            f4v aW = {0.f,0.f,0.f,0.f}, aU = {0.f,0.f,0.f,0.f}, aM = {0.f,0.f,0.f,0.f};
            #pragma unroll
            for (int i = 0; i < 8; ++i){
                s8v w0 = *(const s8v*)(br + i*32);
                s8v u0 = *(const s8v*)(bu + i*32);
                s8v m0 = *(const s8v*)(bm + i*32);
                aW = __builtin_amdgcn_mfma_f32_16x16x32_bf16(xa[i], w0, aW, 0, 0, 0);
                aU = __builtin_amdgcn_mfma_f32_16x16x32_bf16(xa[i], u0, aU, 0, 0, 0);
                aM = __builtin_amdgcn_mfma_f32_16x16x32_bf16(xa[i], m0, aM, 0, 0, 0);
            }
            #pragma unroll
            for (int r = 0; r < 4; ++r) hacc[r] = aW[r] + uaf*aU[r] + ubf*aM[r];
        }
        // local chunks: static 8-unroll, cf=0 pads; scores in regs feed PV directly
        const unsigned short* Xl = Xb + ((size_t)l*128 + b*64 + sbase)*4096;
        const unsigned short* Gl = GT + ((size_t)l*128 + b*64 + sbase)*4096;
        #pragma unroll
        for (int n = 0; n < 8; ++n){
            float cf = cfp[n];
            const unsigned short* Xr = Xl + (size_t)n*4096 + m16*256 + q16*8;
            f4v st  = {0.f,0.f,0.f,0.f};
            f4v st2 = {0.f,0.f,0.f,0.f};
            #pragma unroll
            for (int i = 0; i < 8; i += 2){
                s8v A0 = *(const s8v*)(Xr + i*32);
                s8v A1 = *(const s8v*)(Xr + (i+1)*32);
                st  = __builtin_amdgcn_mfma_f32_16x16x32_bf16(A0, xa[i],   st,  0, 0, 0);
                st2 = __builtin_amdgcn_mfma_f32_16x16x32_bf16(A1, xa[i+1], st2, 0, 0, 0);
            }
            h4 sa;
            #pragma unroll
            for (int r = 0; r < 4; ++r) sa[r] = (_Float16)((st[r] + st2[r])*cf);
            h4 gb = ldh4(Gl + (size_t)n*4096 + (size_t)(n0 + m16)*16 + q16*4);
            hacc = __builtin_amdgcn_mfma_f32_16x16x16f16(sa, gb, hacc, 0, 0, 0);
        }
        if (l < 3){
            #pragma unroll
            for (int r = 0; r < 4; ++r)
                xc[(l + 1) & 1][4*q16 + r][n0 + m16] = f2b(silu_(hacc[r]));
            __syncthreads();
        }
    }

    // epilogue: post rmsnorm + shift + store
    float part[4];
    #pragma unroll
    for (int r = 0; r < 4; ++r) part[r] = hacc[r]*hacc[r];
    #pragma unroll
    for (int off = 1; off < 16; off <<= 1)
        #pragma unroll
        for (int r = 0; r < 4; ++r) part[r] += __shfl_xor(part[r], off, 64);
    if (m16 == 0)
        #pragma unroll
        for (int r = 0; r < 4; ++r) red[w][4*q16 + r] = part[r];
    __syncthreads();
    if (tid < 16){
        float s = 0.f;
        #pragma unroll
        for (int i = 0; i < 16; ++i) s += red[i][tid];
        rs[tid] = rsqrtf(s*(1.f/256.f) + EPSf);
    }
    __syncthreads();
    {
        int d = n0 + m16;
        float wp = wpost[d];
        #pragma unroll
        for (int r = 0; r < 4; ++r){
            int c = 4*q16 + r;
            int tp = nl*16 + c + 15;
            if (tp < 1024)
                out[((size_t)b*1024 + tp)*256 + d] = hacc[r]*rs[c]*wp;
        }
    }
    if (nl == 0){
        for (int idx = tid; idx < 15*256; idx += 1024)
            out[(size_t)b*262144 + idx] = 0.f;
    }
}

extern "C" void kernel_launch(void* const* d_in, const int* in_sizes, int n_in,
                              void* d_out, int out_size, void* d_ws, size_t ws_size,
                              hipStream_t stream) {
    const float* seq     = (const float*)d_in[0];
    const float* w_store = (const float*)d_in[1];
    const float* w_retr  = (const float*)d_in[2];
    const float* w_post  = (const float*)d_in[3];
    const float* Wq      = (const float*)d_in[4];
    const float* Wkv     = (const float*)d_in[5];
    const float* w_adapt = (const float*)d_in[6];
    const float* w_mom   = (const float*)d_in[7];
    const float* w_decay = (const float*)d_in[8];
    const float* W0      = (const float*)d_in[9];
    const float* W1      = (const float*)d_in[10];
    const float* W2      = (const float*)d_in[11];
    const float* W3      = (const float*)d_in[12];

    float* momg  = (float*)d_ws;                       // 128
    float* decg  = momg + NCn;                         // 128
    float* coefb = decg + NCn;                         // 8192
    float* mpb   = coefb + (size_t)NCn*64;             // 8192
    float* apg   = mpb + (size_t)NCn*64;               // 128
    float* bpg   = apg + NCn;                          // 128
    float* mpg   = bpg + NCn;                          // 128
    unsigned short* snb   = (unsigned short*)(mpg + NCn + 32);
    unsigned short* rnb   = snb   + (size_t)NCn*4096;
    unsigned short* WTb   = rnb   + (size_t)NCn*4096;
    unsigned short* Wb    = WTb   + 4*(size_t)DDn;
    unsigned short* WqTb  = Wb    + 3*(size_t)DDn;
    unsigned short* WkvTb = WqTb  + (size_t)DDn;
    unsigned short* Xb    = WkvTb + 2*(size_t)DDn;       // bf16 [l][g][c][d], 4 MB
    unsigned short* XT    = Xb    + (size_t)4*NCn*4096;  // f16  [l][g][d][c], 4 MB
    unsigned short* GT    = XT    + (size_t)4*NCn*4096;  // f16  [l][g][d][c], 4 MB
    unsigned short* ucpb  = GT    + (size_t)4*NCn*4096;  // bf16 [bl][7][256][256]
    unsigned short* mcpb  = ucpb  + (size_t)8*7*65536;   // bf16 [bl][7][256][256]

    ktw   <<<dim3(8, 16, 9), 256,  0, stream>>>(Wq, Wkv, W0, W1, W2, W3,
                                                WTb, WqTb, WkvTb, Wb);
    knorm <<<dim3(2048),     256,  0, stream>>>(seq, w_store, w_retr, snb, rnb);
    kfb   <<<dim3(NCn),      1024, 0, stream>>>(snb, WkvTb, WTb, Wb,
                                                w_adapt, w_mom, w_decay,
                                                momg, decg, Xb, XT, GT);
    kcoef <<<dim3(2),        64,   0, stream>>>(momg, decg, coefb, mpb, apg, bpg, mpg);
    kck   <<<dim3(4, 8),     256,  0, stream>>>(XT, GT, coefb, mpb, apg, bpg, mpg,
                                                ucpb, mcpb);
    kretr <<<dim3(NCn),      1024, 0, stream>>>(rnb, WqTb, WTb, ucpb, mcpb, Xb, GT,
                                                coefb, apg, bpg, w_post, (float*)d_out);
}

// Round 8
// 335.619 us; speedup vs baseline: 1.6675x; 1.6675x over previous
//
#include <hip/hip_runtime.h>
#include <hip/hip_bf16.h>

typedef __attribute__((ext_vector_type(8)))  short s8v;   // 8 bf16
typedef __attribute__((ext_vector_type(4)))  float f4v;   // 16x16 C/D
typedef _Float16 h4 __attribute__((ext_vector_type(4)));  // 4 f16
typedef _Float16 h8 __attribute__((ext_vector_type(8)));  // 8 f16
typedef __attribute__((ext_vector_type(4))) unsigned short u4v;

constexpr int NCn  = 128;
constexpr int DDn  = 65536;
constexpr int XP   = 264;             // padded LDS row (bf16 elems)
constexpr float EPSf = 1.1920929e-07f;

__device__ __forceinline__ float sigm(float x){ return 1.0f/(1.0f + expf(-x)); }
__device__ __forceinline__ float silu_(float x){ return x * sigm(x); }
__device__ __forceinline__ float dsilu_(float x){ float s = sigm(x); return s*(1.0f + x*(1.0f - s)); }

__device__ __forceinline__ unsigned short f2b(float x){
    __hip_bfloat16 b = __float2bfloat16(x);
    unsigned short u; __builtin_memcpy(&u, &b, 2); return u;
}
__device__ __forceinline__ float b2f(unsigned short u){
    __hip_bfloat16 b; __builtin_memcpy(&b, &u, 2); return __bfloat162float(b);
}
__device__ __forceinline__ h4 ldh4(const unsigned short* p){
    h4 r; __builtin_memcpy(&r, p, 8); return r;
}

__device__ __forceinline__ float block_sum(float v, float* red){   // 256 thr
    #pragma unroll
    for (int off = 32; off; off >>= 1) v += __shfl_down(v, off, 64);
    if ((threadIdx.x & 63) == 0) red[threadIdx.x >> 6] = v;
    __syncthreads();
    float r = red[0] + red[1] + red[2] + red[3];
    __syncthreads();
    return r;
}

// ---- merged weight prep: z 0..5 tiled transpose fp32->bf16, z 6..8 cast-copy ----
__global__ __launch_bounds__(256) void ktw(const float* __restrict__ Wq,
        const float* __restrict__ Wkv, const float* __restrict__ W0,
        const float* __restrict__ W1, const float* __restrict__ W2,
        const float* __restrict__ W3, unsigned short* __restrict__ WTb,
        unsigned short* __restrict__ WqTb, unsigned short* __restrict__ WkvTb,
        unsigned short* __restrict__ Wb){
    int z = blockIdx.z;
    if (z >= 6){
        const float* S = (z==6)?W1:(z==7)?W2:W3;
        size_t idx = (((size_t)blockIdx.y*8 + blockIdx.x)*256 + threadIdx.x)*2;
        float2 v = *(const float2*)(S + idx);
        ushort2 u; u.x = f2b(v.x); u.y = f2b(v.y);
        *(ushort2*)(Wb + (size_t)(z-6)*DDn + idx) = u;
        return;
    }
    __shared__ float tl[32][33];
    if (z != 5 && blockIdx.y >= 8) return;
    const float* S; unsigned short* T; int C;
    if (z < 4){ S = (z==0)?W0:(z==1)?W1:(z==2)?W2:W3; T = WTb + (size_t)z*DDn; C = 256; }
    else if (z == 4){ S = Wq; T = WqTb; C = 256; }
    else { S = Wkv; T = WkvTb; C = 512; }
    int k0 = blockIdx.x*32, j0 = blockIdx.y*32;
    int tx = threadIdx.x & 31, ty = threadIdx.x >> 5;
    #pragma unroll
    for (int p = 0; p < 4; ++p)
        tl[ty + 8*p][tx] = S[(size_t)(k0 + ty + 8*p)*C + j0 + tx];
    __syncthreads();
    #pragma unroll
    for (int p = 0; p < 4; ++p)
        T[(size_t)(j0 + ty + 8*p)*256 + k0 + tx] = f2b(tl[tx][ty + 8*p]);
}

// ---- per-token norm, scatter sn + shifted rn ----
__global__ __launch_bounds__(256) void knorm(const float* __restrict__ seq,
        const float* __restrict__ wsn, const float* __restrict__ wrn,
        unsigned short* __restrict__ snb, unsigned short* __restrict__ rnb){
    __shared__ float red[4];
    int t = blockIdx.x, d = threadIdx.x;
    int b = t >> 10, tl = t & 1023, g = t >> 4, c = tl & 15;
    float x = seq[(size_t)t*256 + d];
    float ss = block_sum(x*x, red);
    float xr = x * rsqrtf(ss*(1.f/256.f) + EPSf);
    snb[(size_t)g*4096 + c*256 + d] = f2b(xr*wsn[d]);
    if (tl >= 15){
        int tl2 = tl - 15, g2 = b*64 + (tl2 >> 4), c2 = tl2 & 15;
        rnb[(size_t)g2*4096 + c2*256 + d] = f2b(xr*wrn[d]);
    }
    if (tl >= 1009)
        rnb[(size_t)g*4096 + c*256 + d] = 0;
}

// ---- fwd + bwd dgrads + fused gates, one block per group, 16 waves ----
// writes Xb bf16 [l][g][c][d], XT f16 [l][g][d][c], GT f16 [l][g][d][c]
__global__ __launch_bounds__(1024, 1) void kfb(const unsigned short* __restrict__ snb,
        const unsigned short* __restrict__ WkvTb, const unsigned short* __restrict__ WTb,
        const unsigned short* __restrict__ Wb,
        const float* __restrict__ wa, const float* __restrict__ wm,
        const float* __restrict__ wdk,
        float* __restrict__ momg, float* __restrict__ decg,
        unsigned short* __restrict__ Xb, unsigned short* __restrict__ XT,
        unsigned short* __restrict__ GT){
    __shared__ unsigned short xl[4][16][XP];
    __shared__ unsigned short Gs[16][XP];
    __shared__ float red3[16][4];
    int tid = threadIdx.x, w = tid >> 6, lane = tid & 63;
    int m16 = lane & 15, q16 = lane >> 4;
    int g = blockIdx.x;
    int n0 = w*16;

    float sc;
    {   // fused gates: one reduction pass, one barrier
        int d2 = tid & 255, qt = tid >> 8;
        float a = 0.f;
        #pragma unroll
        for (int c = 0; c < 4; ++c)
            a += b2f(snb[(size_t)g*4096 + (qt*4 + c)*256 + d2]);
        float cm = a * (1.f/16.f);
        float s0 = cm*wa[d2], s1 = cm*wm[d2], s2 = cm*wdk[d2];
        #pragma unroll
        for (int off = 32; off; off >>= 1){
            s0 += __shfl_down(s0, off, 64);
            s1 += __shfl_down(s1, off, 64);
            s2 += __shfl_down(s2, off, 64);
        }
        if (lane == 0){ red3[w][0] = s0; red3[w][1] = s1; red3[w][2] = s2; }
        __syncthreads();
        float da = 0.f, dm = 0.f, dc = 0.f;
        #pragma unroll
        for (int i = 0; i < 16; ++i){
            da += red3[i][0]; dm += red3[i][1]; dc += red3[i][2];
        }
        sc = -2.f * sigm(da) * (1.f/256.f);
        if (tid == 0){ momg[g] = sigm(dm); decg[g] = sigm(dc); }
    }

    s8v af[8];
    const unsigned short* arow = snb + (size_t)g*4096 + m16*256 + q16*8;
    #pragma unroll
    for (int i = 0; i < 8; ++i) af[i] = *(const s8v*)(arow + i*32);

    f4v vacc;
    {
        f4v ka = {0.f,0.f,0.f,0.f}, va = {0.f,0.f,0.f,0.f};
        const unsigned short* brK = WkvTb + (size_t)(n0 + m16)*256 + q16*8;
        const unsigned short* brV = WkvTb + (size_t)(256 + n0 + m16)*256 + q16*8;
        #pragma unroll
        for (int i = 0; i < 8; ++i){
            s8v bK = *(const s8v*)(brK + i*32);
            s8v bV = *(const s8v*)(brV + i*32);
            ka = __builtin_amdgcn_mfma_f32_16x16x32_bf16(af[i], bK, ka, 0, 0, 0);
            va = __builtin_amdgcn_mfma_f32_16x16x32_bf16(af[i], bV, va, 0, 0, 0);
        }
        vacc = va;
        #pragma unroll
        for (int r = 0; r < 4; ++r) xl[0][4*q16 + r][n0 + m16] = f2b(ka[r]);
    }

    f4v hreg[3];
    for (int l = 0; l < 3; ++l){
        __syncthreads();
        s8v xa[8];
        #pragma unroll
        for (int i = 0; i < 8; ++i)
            xa[i] = *(const s8v*)(&xl[l][m16][q16*8 + i*32]);
        const unsigned short* Wt = WTb + (size_t)l*DDn;
        f4v acc = {0.f,0.f,0.f,0.f};
        const unsigned short* br = Wt + (size_t)(n0 + m16)*256 + q16*8;
        #pragma unroll
        for (int i = 0; i < 8; ++i){
            s8v b = *(const s8v*)(br + i*32);
            acc = __builtin_amdgcn_mfma_f32_16x16x32_bf16(xa[i], b, acc, 0, 0, 0);
        }
        hreg[l] = acc;
        #pragma unroll
        for (int r = 0; r < 4; ++r)
            xl[l+1][4*q16 + r][n0 + m16] = f2b(silu_(acc[r]));
    }
    __syncthreads();

    {   // dump layer inputs Xb[l][g][c][d] bf16 (direct copy from xl)
        int c = tid >> 6, d4 = (tid & 63)*4;
        #pragma unroll
        for (int l = 0; l < 4; ++l)
            *(u4v*)(Xb + (((size_t)l*128 + g)*16 + c)*256 + d4) =
                *(const u4v*)(&xl[l][c][d4]);
    }
    {   // dump XT f16 [l][g][d][c]
        int d = tid & 255, qt = tid >> 8;
        #pragma unroll
        for (int l = 0; l < 4; ++l){
            h4 v;
            #pragma unroll
            for (int j = 0; j < 4; ++j)
                v[j] = (_Float16)b2f(xl[l][qt*4 + j][d]);
            *(h4*)(XT + (((size_t)l*128 + g)*256 + d)*16 + qt*4) = v;
        }
    }

    {   // layer 3 (pred) -> Gs
        s8v xa[8];
        #pragma unroll
        for (int i = 0; i < 8; ++i)
            xa[i] = *(const s8v*)(&xl[3][m16][q16*8 + i*32]);
        const unsigned short* Wt = WTb + (size_t)3*DDn;
        f4v acc = {0.f,0.f,0.f,0.f};
        const unsigned short* br = Wt + (size_t)(n0 + m16)*256 + q16*8;
        #pragma unroll
        for (int i = 0; i < 8; ++i){
            s8v b = *(const s8v*)(br + i*32);
            acc = __builtin_amdgcn_mfma_f32_16x16x32_bf16(xa[i], b, acc, 0, 0, 0);
        }
        #pragma unroll
        for (int r = 0; r < 4; ++r)
            Gs[4*q16 + r][n0 + m16] = f2b(sc * (acc[r] - vacc[r]));
    }
    __syncthreads();
    {   // write f16 GT[3][g][d][c]
        int d = tid & 255, qt = tid >> 8;
        h4 v;
        #pragma unroll
        for (int j = 0; j < 4; ++j)
            v[j] = (_Float16)b2f(Gs[qt*4 + j][d]);
        *(h4*)(GT + (((size_t)3*128 + g)*256 + d)*16 + qt*4) = v;
    }

    for (int l = 3; l >= 1; --l){
        s8v gfa[8];
        #pragma unroll
        for (int i = 0; i < 8; ++i)
            gfa[i] = *(const s8v*)(&Gs[m16][q16*8 + i*32]);
        const unsigned short* Wr = Wb + (size_t)(l-1)*DDn;
        f4v acc = {0.f,0.f,0.f,0.f};
        const unsigned short* br = Wr + (size_t)(n0 + m16)*256 + q16*8;
        #pragma unroll
        for (int i = 0; i < 8; ++i){
            s8v b = *(const s8v*)(br + i*32);
            acc = __builtin_amdgcn_mfma_f32_16x16x32_bf16(gfa[i], b, acc, 0, 0, 0);
        }
        f4v gn;
        #pragma unroll
        for (int r = 0; r < 4; ++r)
            gn[r] = acc[r] * dsilu_(hreg[l-1][r]);
        __syncthreads();
        #pragma unroll
        for (int r = 0; r < 4; ++r)
            Gs[4*q16 + r][n0 + m16] = f2b(gn[r]);
        __syncthreads();
        {
            int d = tid & 255, qt = tid >> 8;
            h4 v;
            #pragma unroll
            for (int j = 0; j < 4; ++j)
                v[j] = (_Float16)b2f(Gs[qt*4 + j][d]);
            *(h4*)(GT + (((size_t)(l-1)*128 + g)*256 + d)*16 + qt*4) = v;
        }
    }
}

// ---- coefficients: cf(g,n), mp(g,n), and per-g segment scalars A_g,B_g,PImo_g ----
__global__ __launch_bounds__(64) void kcoef(const float* __restrict__ momg,
        const float* __restrict__ decg, float* __restrict__ coefb,
        float* __restrict__ mpb, float* __restrict__ apg,
        float* __restrict__ bpg, float* __restrict__ mpg){
    int b = blockIdx.x, n = threadIdx.x;
    float M = 0.f, cf = 0.f;
    for (int gg = 0; gg < 64; ++gg){
        float mo = momg[b*64 + gg], de = 1.f - decg[b*64 + gg];
        if (gg == n){ M = 1.f; cf = 1.f; }
        else if (gg > n){ M *= mo; cf = de*cf + M; }
        coefb[((size_t)b*64 + gg)*64 + n] = cf;
        mpb  [((size_t)b*64 + gg)*64 + n] = M;
    }
    int ss0 = n & ~7;
    float a = 1.f, B = 0.f, pm = 1.f;
    for (int j = ss0; j <= n; ++j){
        float mo = momg[b*64 + j], de = 1.f - decg[b*64 + j];
        pm *= mo; B = de*B + pm; a *= de;
    }
    apg[b*64 + n] = a; bpg[b*64 + n] = B; mpg[b*64 + n] = pm;
}

// ---- fused segment partials + scan -> bf16 checkpoints Ucp/Mcp ----
// grid (16 rowtiles, 16 coltiles, 8 bl), 1 wave/block; scan state = 8 VGPR (no spill)
__global__ __launch_bounds__(64, 1) void kck(const unsigned short* __restrict__ XT,
        const unsigned short* __restrict__ GT, const float* __restrict__ coefb,
        const float* __restrict__ mpb, const float* __restrict__ apg,
        const float* __restrict__ bpg, const float* __restrict__ mpg,
        unsigned short* __restrict__ ucpb, unsigned short* __restrict__ mcpb){
    int lane = threadIdx.x;
    int m16 = lane & 15, q16 = lane >> 4;
    int rt = blockIdx.x, ct = blockIdx.y, bl = blockIdx.z;
    int b = bl >> 2, l = bl & 3;
    int dr = rt*16 + m16;   // G row (dout)
    int dc = ct*16 + m16;   // X row (din)
    const unsigned short* Gb = GT + ((size_t)l*128 + b*64)*4096 + (size_t)dr*16 + q16*4;
    const unsigned short* Xb2 = XT + ((size_t)l*128 + b*64)*4096 + (size_t)dc*16 + q16*4;
    f4v us = {0.f,0.f,0.f,0.f}, ms = {0.f,0.f,0.f,0.f};
    for (int s = 0; s < 7; ++s){
        int e = b*64 + s*8 + 7;
        float av = apg[e], bv = bpg[e], mv = mpg[e];
        const float* cfr = coefb + (size_t)e*64 + s*8;
        const float* mpr = mpb   + (size_t)e*64 + s*8;
        f4v acu = {0.f,0.f,0.f,0.f}, acm = {0.f,0.f,0.f,0.f};
        #pragma unroll
        for (int n = 0; n < 8; ++n){
            h4 a  = ldh4(Gb  + (size_t)(s*8 + n)*4096);
            h4 xb = ldh4(Xb2 + (size_t)(s*8 + n)*4096);
            _Float16 cfh = (_Float16)cfr[n];
            _Float16 mph = (_Float16)mpr[n];
            acu = __builtin_amdgcn_mfma_f32_16x16x16f16(a*cfh, xb, acu, 0, 0, 0);
            acm = __builtin_amdgcn_mfma_f32_16x16x16f16(a*mph, xb, acm, 0, 0, 0);
        }
        size_t ob = (((size_t)bl*7 + s)*256 + (size_t)(rt*16))*256 + ct*16 + m16;
        #pragma unroll
        for (int r = 0; r < 4; ++r){
            float un = av*us[r] + bv*ms[r] + acu[r];
            float mn = mv*ms[r] + acm[r];
            us[r] = un; ms[r] = mn;
            ucpb[ob + (size_t)(4*q16 + r)*256] = f2b(un);
            mcpb[ob + (size_t)(4*q16 + r)*256] = f2b(mn);
        }
    }
}

// ---- retrieval: q-proj + 4 layers {x@(W + A*Ucp + B*Mcp) + <=8 local chunks} ----
// one block per group; 16 waves; 1 barrier/layer; scores redundant per-wave in regs
__global__ __launch_bounds__(1024, 1) void kretr(const unsigned short* __restrict__ rnb,
        const unsigned short* __restrict__ WqTb, const unsigned short* __restrict__ WTb,
        const unsigned short* __restrict__ ucpb, const unsigned short* __restrict__ mcpb,
        const unsigned short* __restrict__ Xb, const unsigned short* __restrict__ GT,
        const float* __restrict__ coefb, const float* __restrict__ apg,
        const float* __restrict__ bpg, const float* __restrict__ wpost,
        float* __restrict__ out){
    __shared__ unsigned short xc[2][16][XP];
    __shared__ float red[16][16];
    __shared__ float rs[16];
    int tid = threadIdx.x, w = tid >> 6, lane = tid & 63;
    int m16 = lane & 15, q16 = lane >> 4;
    // XCD swizzle: co-locate the 8 blocks sharing a (b,seg) checkpoint on one XCD
    int B = blockIdx.x;
    int g = (((B & 7)*2) + ((B >> 3) & 1))*8 + (B >> 4);
    int b = g >> 6, nl = g & 63;
    int seg = nl >> 3, sbase = seg*8;
    int segm1 = seg ? seg - 1 : 0;
    float uaf = seg ? apg[g] : 0.f;
    float ubf = seg ? bpg[g] : 0.f;
    int n0 = w*16;

    {   // q-projection
        s8v a[8];
        const unsigned short* ar = rnb + (size_t)g*4096 + m16*256 + q16*8;
        #pragma unroll
        for (int i = 0; i < 8; ++i) a[i] = *(const s8v*)(ar + i*32);
        f4v acc = {0.f,0.f,0.f,0.f};
        const unsigned short* br = WqTb + (size_t)(n0 + m16)*256 + q16*8;
        #pragma unroll
        for (int i = 0; i < 8; ++i){
            s8v bb = *(const s8v*)(br + i*32);
            acc = __builtin_amdgcn_mfma_f32_16x16x32_bf16(a[i], bb, acc, 0, 0, 0);
        }
        #pragma unroll
        for (int r = 0; r < 4; ++r) xc[0][4*q16 + r][n0 + m16] = f2b(acc[r]);
    }
    __syncthreads();

    const float* cfp = coefb + (size_t)g*64 + sbase;   // zeros past nl (kcoef init)
    f4v hacc;
    for (int l = 0; l < 4; ++l){
        s8v xa[8];
        #pragma unroll
        for (int i = 0; i < 8; ++i)
            xa[i] = *(const s8v*)(&xc[l & 1][m16][q16*8 + i*32]);
        // dense: x @ (W + A*Ucp + B*Mcp)  (uniform path; seg==0 scales by 0)
        {
            const unsigned short* br = WTb + (size_t)l*DDn + (size_t)(n0 + m16)*256 + q16*8;
            size_t cko = ((size_t)(b*4 + l)*7 + segm1)*65536 + (size_t)(n0 + m16)*256 + q16*8;
            const unsigned short* bu = ucpb + cko;
            const unsigned short* bm = mcpb + cko;
            f4v aW = {0.f,0.f,0.f,0.f}, aU = {0.f,0.f,0.f,0.f}, aM = {0.f,0.f,0.f,0.f};
            #pragma unroll
            for (int i = 0; i < 8; ++i){
                s8v w0 = *(const s8v*)(br + i*32);
                s8v u0 = *(const s8v*)(bu + i*32);
                s8v m0 = *(const s8v*)(bm + i*32);
                aW = __builtin_amdgcn_mfma_f32_16x16x32_bf16(xa[i], w0, aW, 0, 0, 0);
                aU = __builtin_amdgcn_mfma_f32_16x16x32_bf16(xa[i], u0, aU, 0, 0, 0);
                aM = __builtin_amdgcn_mfma_f32_16x16x32_bf16(xa[i], m0, aM, 0, 0, 0);
            }
            #pragma unroll
            for (int r = 0; r < 4; ++r) hacc[r] = aW[r] + uaf*aU[r] + ubf*aM[r];
        }
        // local chunks: static 8-unroll, cf=0 pads; scores in regs feed PV directly
        const unsigned short* Xl = Xb + ((size_t)l*128 + b*64 + sbase)*4096;
        const unsigned short* Gl = GT + ((size_t)l*128 + b*64 + sbase)*4096;
        #pragma unroll
        for (int n = 0; n < 8; ++n){
            float cf = cfp[n];
            const unsigned short* Xr = Xl + (size_t)n*4096 + m16*256 + q16*8;
            f4v st  = {0.f,0.f,0.f,0.f};
            f4v st2 = {0.f,0.f,0.f,0.f};
            #pragma unroll
            for (int i = 0; i < 8; i += 2){
                s8v A0 = *(const s8v*)(Xr + i*32);
                s8v A1 = *(const s8v*)(Xr + (i+1)*32);
                st  = __builtin_amdgcn_mfma_f32_16x16x32_bf16(A0, xa[i],   st,  0, 0, 0);
                st2 = __builtin_amdgcn_mfma_f32_16x16x32_bf16(A1, xa[i+1], st2, 0, 0, 0);
            }
            h4 sa;
            #pragma unroll
            for (int r = 0; r < 4; ++r) sa[r] = (_Float16)((st[r] + st2[r])*cf);
            h4 gb = ldh4(Gl + (size_t)n*4096 + (size_t)(n0 + m16)*16 + q16*4);
            hacc = __builtin_amdgcn_mfma_f32_16x16x16f16(sa, gb, hacc, 0, 0, 0);
        }
        if (l < 3){
            #pragma unroll
            for (int r = 0; r < 4; ++r)
                xc[(l + 1) & 1][4*q16 + r][n0 + m16] = f2b(silu_(hacc[r]));
            __syncthreads();
        }
    }

    // epilogue: post rmsnorm + shift + store
    float part[4];
    #pragma unroll
    for (int r = 0; r < 4; ++r) part[r] = hacc[r]*hacc[r];
    #pragma unroll
    for (int off = 1; off < 16; off <<= 1)
        #pragma unroll
        for (int r = 0; r < 4; ++r) part[r] += __shfl_xor(part[r], off, 64);
    if (m16 == 0)
        #pragma unroll
        for (int r = 0; r < 4; ++r) red[w][4*q16 + r] = part[r];
    __syncthreads();
    if (tid < 16){
        float s = 0.f;
        #pragma unroll
        for (int i = 0; i < 16; ++i) s += red[i][tid];
        rs[tid] = rsqrtf(s*(1.f/256.f) + EPSf);
    }
    __syncthreads();
    {
        int d = n0 + m16;
        float wp = wpost[d];
        #pragma unroll
        for (int r = 0; r < 4; ++r){
            int c = 4*q16 + r;
            int tp = nl*16 + c + 15;
            if (tp < 1024)
                out[((size_t)b*1024 + tp)*256 + d] = hacc[r]*rs[c]*wp;
        }
    }
    if (nl == 0){
        for (int idx = tid; idx < 15*256; idx += 1024)
            out[(size_t)b*262144 + idx] = 0.f;
    }
}

extern "C" void kernel_launch(void* const* d_in, const int* in_sizes, int n_in,
                              void* d_out, int out_size, void* d_ws, size_t ws_size,
                              hipStream_t stream) {
    const float* seq     = (const float*)d_in[0];
    const float* w_store = (const float*)d_in[1];
    const float* w_retr  = (const float*)d_in[2];
    const float* w_post  = (const float*)d_in[3];
    const float* Wq      = (const float*)d_in[4];
    const float* Wkv     = (const float*)d_in[5];
    const float* w_adapt = (const float*)d_in[6];
    const float* w_mom   = (const float*)d_in[7];
    const float* w_decay = (const float*)d_in[8];
    const float* W0      = (const float*)d_in[9];
    const float* W1      = (const float*)d_in[10];
    const float* W2      = (const float*)d_in[11];
    const float* W3      = (const float*)d_in[12];

    float* momg  = (float*)d_ws;                       // 128
    float* decg  = momg + NCn;                         // 128
    float* coefb = decg + NCn;                         // 8192
    float* mpb   = coefb + (size_t)NCn*64;             // 8192
    float* apg   = mpb + (size_t)NCn*64;               // 128
    float* bpg   = apg + NCn;                          // 128
    float* mpg   = bpg + NCn;                          // 128
    unsigned short* snb   = (unsigned short*)(mpg + NCn + 32);
    unsigned short* rnb   = snb   + (size_t)NCn*4096;
    unsigned short* WTb   = rnb   + (size_t)NCn*4096;
    unsigned short* Wb    = WTb   + 4*(size_t)DDn;
    unsigned short* WqTb  = Wb    + 3*(size_t)DDn;
    unsigned short* WkvTb = WqTb  + (size_t)DDn;
    unsigned short* Xb    = WkvTb + 2*(size_t)DDn;       // bf16 [l][g][c][d], 4 MB
    unsigned short* XT    = Xb    + (size_t)4*NCn*4096;  // f16  [l][g][d][c], 4 MB
    unsigned short* GT    = XT    + (size_t)4*NCn*4096;  // f16  [l][g][d][c], 4 MB
    unsigned short* ucpb  = GT    + (size_t)4*NCn*4096;  // bf16 [bl][7][256][256]
    unsigned short* mcpb  = ucpb  + (size_t)8*7*65536;   // bf16 [bl][7][256][256]

    ktw   <<<dim3(8, 16, 9), 256,  0, stream>>>(Wq, Wkv, W0, W1, W2, W3,
                                                WTb, WqTb, WkvTb, Wb);
    knorm <<<dim3(2048),     256,  0, stream>>>(seq, w_store, w_retr, snb, rnb);
    kfb   <<<dim3(NCn),      1024, 0, stream>>>(snb, WkvTb, WTb, Wb,
                                                w_adapt, w_mom, w_decay,
                                                momg, decg, Xb, XT, GT);
    kcoef <<<dim3(2),        64,   0, stream>>>(momg, decg, coefb, mpb, apg, bpg, mpg);
    kck   <<<dim3(16, 16, 8), 64,  0, stream>>>(XT, GT, coefb, mpb, apg, bpg, mpg,
                                                ucpb, mcpb);
    kretr <<<dim3(NCn),      1024, 0, stream>>>(rnb, WqTb, WTb, ucpb, mcpb, Xb, GT,
                                                coefb, apg, bpg, w_post, (float*)d_out);
}

// Round 9
// 233.683 us; speedup vs baseline: 2.3949x; 1.4362x over previous
//
#include <hip/hip_runtime.h>
#include <hip/hip_bf16.h>

typedef __attribute__((ext_vector_type(8)))  short s8v;   // 8 bf16
typedef __attribute__((ext_vector_type(4)))  float f4v;   // 16x16 C/D
typedef _Float16 h4 __attribute__((ext_vector_type(4)));  // 4 f16
typedef _Float16 h8 __attribute__((ext_vector_type(8)));  // 8 f16
typedef __attribute__((ext_vector_type(4))) unsigned short u4v;

constexpr int NCn  = 128;
constexpr int DDn  = 65536;
constexpr int XP   = 264;             // padded LDS row (bf16 elems)
constexpr int SSP  = 24;              // padded score row (f16 elems, 48B)
constexpr float EPSf = 1.1920929e-07f;

__device__ __forceinline__ float sigm(float x){ return 1.0f/(1.0f + expf(-x)); }
__device__ __forceinline__ float silu_(float x){ return x * sigm(x); }
__device__ __forceinline__ float dsilu_(float x){ float s = sigm(x); return s*(1.0f + x*(1.0f - s)); }

__device__ __forceinline__ unsigned short f2b(float x){
    __hip_bfloat16 b = __float2bfloat16(x);
    unsigned short u; __builtin_memcpy(&u, &b, 2); return u;
}
__device__ __forceinline__ float b2f(unsigned short u){
    __hip_bfloat16 b; __builtin_memcpy(&b, &u, 2); return __bfloat162float(b);
}
__device__ __forceinline__ h4 ldh4(const unsigned short* p){
    h4 r; __builtin_memcpy(&r, p, 8); return r;
}
__device__ __forceinline__ h8 ldh8(const void* p){
    h8 r; __builtin_memcpy(&r, p, 16); return r;
}

__device__ __forceinline__ float block_sum(float v, float* red){   // 256 thr
    #pragma unroll
    for (int off = 32; off; off >>= 1) v += __shfl_down(v, off, 64);
    if ((threadIdx.x & 63) == 0) red[threadIdx.x >> 6] = v;
    __syncthreads();
    float r = red[0] + red[1] + red[2] + red[3];
    __syncthreads();
    return r;
}

// ---- merged weight prep: z 0..5 tiled transpose fp32->bf16, z 6..8 cast-copy ----
__global__ __launch_bounds__(256) void ktw(const float* __restrict__ Wq,
        const float* __restrict__ Wkv, const float* __restrict__ W0,
        const float* __restrict__ W1, const float* __restrict__ W2,
        const float* __restrict__ W3, unsigned short* __restrict__ WTb,
        unsigned short* __restrict__ WqTb, unsigned short* __restrict__ WkvTb,
        unsigned short* __restrict__ Wb){
    int z = blockIdx.z;
    if (z >= 6){
        const float* S = (z==6)?W1:(z==7)?W2:W3;
        size_t idx = (((size_t)blockIdx.y*8 + blockIdx.x)*256 + threadIdx.x)*2;
        float2 v = *(const float2*)(S + idx);
        ushort2 u; u.x = f2b(v.x); u.y = f2b(v.y);
        *(ushort2*)(Wb + (size_t)(z-6)*DDn + idx) = u;
        return;
    }
    __shared__ float tl[32][33];
    if (z != 5 && blockIdx.y >= 8) return;
    const float* S; unsigned short* T; int C;
    if (z < 4){ S = (z==0)?W0:(z==1)?W1:(z==2)?W2:W3; T = WTb + (size_t)z*DDn; C = 256; }
    else if (z == 4){ S = Wq; T = WqTb; C = 256; }
    else { S = Wkv; T = WkvTb; C = 512; }
    int k0 = blockIdx.x*32, j0 = blockIdx.y*32;
    int tx = threadIdx.x & 31, ty = threadIdx.x >> 5;
    #pragma unroll
    for (int p = 0; p < 4; ++p)
        tl[ty + 8*p][tx] = S[(size_t)(k0 + ty + 8*p)*C + j0 + tx];
    __syncthreads();
    #pragma unroll
    for (int p = 0; p < 4; ++p)
        T[(size_t)(j0 + ty + 8*p)*256 + k0 + tx] = f2b(tl[tx][ty + 8*p]);
}

// ---- per-token norm, scatter sn + shifted rn ----
__global__ __launch_bounds__(256) void knorm(const float* __restrict__ seq,
        const float* __restrict__ wsn, const float* __restrict__ wrn,
        unsigned short* __restrict__ snb, unsigned short* __restrict__ rnb){
    __shared__ float red[4];
    int t = blockIdx.x, d = threadIdx.x;
    int b = t >> 10, tl = t & 1023, g = t >> 4, c = tl & 15;
    float x = seq[(size_t)t*256 + d];
    float ss = block_sum(x*x, red);
    float xr = x * rsqrtf(ss*(1.f/256.f) + EPSf);
    snb[(size_t)g*4096 + c*256 + d] = f2b(xr*wsn[d]);
    if (tl >= 15){
        int tl2 = tl - 15, g2 = b*64 + (tl2 >> 4), c2 = tl2 & 15;
        rnb[(size_t)g2*4096 + c2*256 + d] = f2b(xr*wrn[d]);
    }
    if (tl >= 1009)
        rnb[(size_t)g*4096 + c*256 + d] = 0;
}

// ---- fwd + bwd dgrads + fused gates, one block per group, 16 waves ----
// writes Xb bf16 [l][g][c][d], XT f16 [l][g][d][c], GT f16 [l][g][d][c]
// cross-barrier weight prefetch: bpre holds next stage's B-frags
__global__ __launch_bounds__(1024, 1) void kfb(const unsigned short* __restrict__ snb,
        const unsigned short* __restrict__ WkvTb, const unsigned short* __restrict__ WTb,
        const unsigned short* __restrict__ Wb,
        const float* __restrict__ wa, const float* __restrict__ wm,
        const float* __restrict__ wdk,
        float* __restrict__ momg, float* __restrict__ decg,
        unsigned short* __restrict__ Xb, unsigned short* __restrict__ XT,
        unsigned short* __restrict__ GT){
    __shared__ unsigned short xl[4][16][XP];
    __shared__ unsigned short Gs[16][XP];
    __shared__ float red3[16][4];
    int tid = threadIdx.x, w = tid >> 6, lane = tid & 63;
    int m16 = lane & 15, q16 = lane >> 4;
    int g = blockIdx.x;
    int n0 = w*16;
    size_t boff = (size_t)(n0 + m16)*256 + q16*8;

    // issue A-frag loads early (hide under gate phase)
    s8v af[8];
    const unsigned short* arow = snb + (size_t)g*4096 + m16*256 + q16*8;
    #pragma unroll
    for (int i = 0; i < 8; ++i) af[i] = *(const s8v*)(arow + i*32);

    float sc;
    {   // fused gates: one reduction pass, one barrier
        int d2 = tid & 255, qt = tid >> 8;
        float a = 0.f;
        #pragma unroll
        for (int c = 0; c < 4; ++c)
            a += b2f(snb[(size_t)g*4096 + (qt*4 + c)*256 + d2]);
        float cm = a * (1.f/16.f);
        float s0 = cm*wa[d2], s1 = cm*wm[d2], s2 = cm*wdk[d2];
        #pragma unroll
        for (int off = 32; off; off >>= 1){
            s0 += __shfl_down(s0, off, 64);
            s1 += __shfl_down(s1, off, 64);
            s2 += __shfl_down(s2, off, 64);
        }
        if (lane == 0){ red3[w][0] = s0; red3[w][1] = s1; red3[w][2] = s2; }
        __syncthreads();
        float da = 0.f, dm = 0.f, dc = 0.f;
        #pragma unroll
        for (int i = 0; i < 16; ++i){
            da += red3[i][0]; dm += red3[i][1]; dc += red3[i][2];
        }
        sc = -2.f * sigm(da) * (1.f/256.f);
        if (tid == 0){ momg[g] = sigm(dm); decg[g] = sigm(dc); }
    }

    // prefetch layer-0 weights (used after next barrier)
    s8v bpre[8];
    #pragma unroll
    for (int i = 0; i < 8; ++i) bpre[i] = *(const s8v*)(WTb + boff + i*32);

    f4v vacc;
    {
        f4v ka = {0.f,0.f,0.f,0.f}, va = {0.f,0.f,0.f,0.f};
        const unsigned short* brK = WkvTb + boff;
        const unsigned short* brV = WkvTb + (size_t)256*256 + boff;
        #pragma unroll
        for (int i = 0; i < 8; ++i){
            s8v bK = *(const s8v*)(brK + i*32);
            s8v bV = *(const s8v*)(brV + i*32);
            ka = __builtin_amdgcn_mfma_f32_16x16x32_bf16(af[i], bK, ka, 0, 0, 0);
            va = __builtin_amdgcn_mfma_f32_16x16x32_bf16(af[i], bV, va, 0, 0, 0);
        }
        vacc = va;
        #pragma unroll
        for (int r = 0; r < 4; ++r) xl[0][4*q16 + r][n0 + m16] = f2b(ka[r]);
    }

    f4v hreg[3];
    #pragma unroll
    for (int l = 0; l < 3; ++l){
        __syncthreads();
        s8v xa[8];
        #pragma unroll
        for (int i = 0; i < 8; ++i)
            xa[i] = *(const s8v*)(&xl[l][m16][q16*8 + i*32]);
        s8v bcur[8];
        #pragma unroll
        for (int i = 0; i < 8; ++i) bcur[i] = bpre[i];
        const unsigned short* nxt = WTb + (size_t)(l+1)*DDn + boff;
        #pragma unroll
        for (int i = 0; i < 8; ++i) bpre[i] = *(const s8v*)(nxt + i*32);
        f4v acc = {0.f,0.f,0.f,0.f};
        #pragma unroll
        for (int i = 0; i < 8; ++i)
            acc = __builtin_amdgcn_mfma_f32_16x16x32_bf16(xa[i], bcur[i], acc, 0, 0, 0);
        hreg[l] = acc;
        #pragma unroll
        for (int r = 0; r < 4; ++r)
            xl[l+1][4*q16 + r][n0 + m16] = f2b(silu_(acc[r]));
    }
    __syncthreads();

    {   // dump layer inputs Xb[l][g][c][d] bf16 (direct copy from xl)
        int c = tid >> 6, d4 = (tid & 63)*4;
        #pragma unroll
        for (int l = 0; l < 4; ++l)
            *(u4v*)(Xb + (((size_t)l*128 + g)*16 + c)*256 + d4) =
                *(const u4v*)(&xl[l][c][d4]);
    }
    {   // dump XT f16 [l][g][d][c]
        int d = tid & 255, qt = tid >> 8;
        #pragma unroll
        for (int l = 0; l < 4; ++l){
            h4 v;
            #pragma unroll
            for (int j = 0; j < 4; ++j)
                v[j] = (_Float16)b2f(xl[l][qt*4 + j][d]);
            *(h4*)(XT + (((size_t)l*128 + g)*256 + d)*16 + qt*4) = v;
        }
    }

    {   // layer 3 (pred) -> Gs; prefetch Wb[2] for bwd l=3
        s8v xa[8];
        #pragma unroll
        for (int i = 0; i < 8; ++i)
            xa[i] = *(const s8v*)(&xl[3][m16][q16*8 + i*32]);
        s8v bcur[8];
        #pragma unroll
        for (int i = 0; i < 8; ++i) bcur[i] = bpre[i];
        const unsigned short* nxt = Wb + (size_t)2*DDn + boff;
        #pragma unroll
        for (int i = 0; i < 8; ++i) bpre[i] = *(const s8v*)(nxt + i*32);
        f4v acc = {0.f,0.f,0.f,0.f};
        #pragma unroll
        for (int i = 0; i < 8; ++i)
            acc = __builtin_amdgcn_mfma_f32_16x16x32_bf16(xa[i], bcur[i], acc, 0, 0, 0);
        #pragma unroll
        for (int r = 0; r < 4; ++r)
            Gs[4*q16 + r][n0 + m16] = f2b(sc * (acc[r] - vacc[r]));
    }
    __syncthreads();
    {   // write f16 GT[3][g][d][c]
        int d = tid & 255, qt = tid >> 8;
        h4 v;
        #pragma unroll
        for (int j = 0; j < 4; ++j)
            v[j] = (_Float16)b2f(Gs[qt*4 + j][d]);
        *(h4*)(GT + (((size_t)3*128 + g)*256 + d)*16 + qt*4) = v;
    }

    #pragma unroll
    for (int l = 3; l >= 1; --l){
        s8v gfa[8];
        #pragma unroll
        for (int i = 0; i < 8; ++i)
            gfa[i] = *(const s8v*)(&Gs[m16][q16*8 + i*32]);
        s8v bcur[8];
        #pragma unroll
        for (int i = 0; i < 8; ++i) bcur[i] = bpre[i];
        if (l > 1){
            const unsigned short* nxt = Wb + (size_t)(l-2)*DDn + boff;
            #pragma unroll
            for (int i = 0; i < 8; ++i) bpre[i] = *(const s8v*)(nxt + i*32);
        }
        f4v acc = {0.f,0.f,0.f,0.f};
        #pragma unroll
        for (int i = 0; i < 8; ++i)
            acc = __builtin_amdgcn_mfma_f32_16x16x32_bf16(gfa[i], bcur[i], acc, 0, 0, 0);
        f4v gn;
        #pragma unroll
        for (int r = 0; r < 4; ++r)
            gn[r] = acc[r] * dsilu_(hreg[l-1][r]);
        __syncthreads();
        #pragma unroll
        for (int r = 0; r < 4; ++r)
            Gs[4*q16 + r][n0 + m16] = f2b(gn[r]);
        __syncthreads();
        {
            int d = tid & 255, qt = tid >> 8;
            h4 v;
            #pragma unroll
            for (int j = 0; j < 4; ++j)
                v[j] = (_Float16)b2f(Gs[qt*4 + j][d]);
            *(h4*)(GT + (((size_t)(l-1)*128 + g)*256 + d)*16 + qt*4) = v;
        }
    }
}

// ---- coefficients: cf(g,n), mp(g,n), and per-g segment scalars A_g,B_g,PImo_g ----
__global__ __launch_bounds__(64) void kcoef(const float* __restrict__ momg,
        const float* __restrict__ decg, float* __restrict__ coefb,
        float* __restrict__ mpb, float* __restrict__ apg,
        float* __restrict__ bpg, float* __restrict__ mpg){
    int b = blockIdx.x, n = threadIdx.x;
    float M = 0.f, cf = 0.f;
    for (int gg = 0; gg < 64; ++gg){
        float mo = momg[b*64 + gg], de = 1.f - decg[b*64 + gg];
        if (gg == n){ M = 1.f; cf = 1.f; }
        else if (gg > n){ M *= mo; cf = de*cf + M; }
        coefb[((size_t)b*64 + gg)*64 + n] = cf;
        mpb  [((size_t)b*64 + gg)*64 + n] = M;
    }
    int ss0 = n & ~7;
    float a = 1.f, B = 0.f, pm = 1.f;
    for (int j = ss0; j <= n; ++j){
        float mo = momg[b*64 + j], de = 1.f - decg[b*64 + j];
        pm *= mo; B = de*B + pm; a *= de;
    }
    apg[b*64 + n] = a; bpg[b*64 + n] = B; mpg[b*64 + n] = pm;
}

// ---- fused segment partials + scan -> bf16 checkpoints Ucp/Mcp ----
// grid (16 rowtiles, 16 coltiles, 8 bl), 1 wave/block; scan state = 8 VGPR (no spill)
__global__ __launch_bounds__(64, 1) void kck(const unsigned short* __restrict__ XT,
        const unsigned short* __restrict__ GT, const float* __restrict__ coefb,
        const float* __restrict__ mpb, const float* __restrict__ apg,
        const float* __restrict__ bpg, const float* __restrict__ mpg,
        unsigned short* __restrict__ ucpb, unsigned short* __restrict__ mcpb){
    int lane = threadIdx.x;
    int m16 = lane & 15, q16 = lane >> 4;
    int rt = blockIdx.x, ct = blockIdx.y, bl = blockIdx.z;
    int b = bl >> 2, l = bl & 3;
    int dr = rt*16 + m16;   // G row (dout)
    int dc = ct*16 + m16;   // X row (din)
    const unsigned short* Gb = GT + ((size_t)l*128 + b*64)*4096 + (size_t)dr*16 + q16*4;
    const unsigned short* Xb2 = XT + ((size_t)l*128 + b*64)*4096 + (size_t)dc*16 + q16*4;
    f4v us = {0.f,0.f,0.f,0.f}, ms = {0.f,0.f,0.f,0.f};
    for (int s = 0; s < 7; ++s){
        int e = b*64 + s*8 + 7;
        float av = apg[e], bv = bpg[e], mv = mpg[e];
        const float* cfr = coefb + (size_t)e*64 + s*8;
        const float* mpr = mpb   + (size_t)e*64 + s*8;
        f4v acu = {0.f,0.f,0.f,0.f}, acm = {0.f,0.f,0.f,0.f};
        #pragma unroll
        for (int n = 0; n < 8; ++n){
            h4 a  = ldh4(Gb  + (size_t)(s*8 + n)*4096);
            h4 xb = ldh4(Xb2 + (size_t)(s*8 + n)*4096);
            _Float16 cfh = (_Float16)cfr[n];
            _Float16 mph = (_Float16)mpr[n];
            acu = __builtin_amdgcn_mfma_f32_16x16x16f16(a*cfh, xb, acu, 0, 0, 0);
            acm = __builtin_amdgcn_mfma_f32_16x16x16f16(a*mph, xb, acm, 0, 0, 0);
        }
        size_t ob = (((size_t)bl*7 + s)*256 + (size_t)(rt*16))*256 + ct*16 + m16;
        #pragma unroll
        for (int r = 0; r < 4; ++r){
            float un = av*us[r] + bv*ms[r] + acu[r];
            float mn = mv*ms[r] + acm[r];
            us[r] = un; ms[r] = mn;
            ucpb[ob + (size_t)(4*q16 + r)*256] = f2b(un);
            mcpb[ob + (size_t)(4*q16 + r)*256] = f2b(mn);
        }
    }
}

// ---- retrieval: q-proj + 4 layers {x@(W + A*Ucp + B*Mcp) + <=8 local chunks} ----
// 16 waves; LDS score staging (waves 0-7, one chunk each); pair-batched K=32 f16 PV
// with G prefetched across the barrier; 2 barriers/layer
__global__ __launch_bounds__(1024, 1) void kretr(const unsigned short* __restrict__ rnb,
        const unsigned short* __restrict__ WqTb, const unsigned short* __restrict__ WTb,
        const unsigned short* __restrict__ ucpb, const unsigned short* __restrict__ mcpb,
        const unsigned short* __restrict__ Xb, const unsigned short* __restrict__ GT,
        const float* __restrict__ coefb, const float* __restrict__ apg,
        const float* __restrict__ bpg, const float* __restrict__ wpost,
        float* __restrict__ out){
    __shared__ unsigned short xc[2][16][XP];
    __shared__ _Float16 ss[8][16][SSP];   // [local chunk][j][i]
    __shared__ float red[16][16];
    __shared__ float rs[16];
    int tid = threadIdx.x, w = tid >> 6, lane = tid & 63;
    int m16 = lane & 15, q16 = lane >> 4;
    // XCD swizzle: co-locate the 8 blocks sharing a (b,seg) checkpoint on one XCD
    int B = blockIdx.x;
    int g = (((B & 7)*2) + ((B >> 3) & 1))*8 + (B >> 4);
    int b = g >> 6, nl = g & 63;
    int seg = nl >> 3, sbase = seg*8;
    int segm1 = seg ? seg - 1 : 0;
    float uaf = seg ? apg[g] : 0.f;
    float ubf = seg ? bpg[g] : 0.f;
    int n0 = w*16;
    int c01 = q16 >> 1, koff = (q16 & 1)*8;   // PV pair decomposition

    {   // q-projection
        s8v a[8];
        const unsigned short* ar = rnb + (size_t)g*4096 + m16*256 + q16*8;
        #pragma unroll
        for (int i = 0; i < 8; ++i) a[i] = *(const s8v*)(ar + i*32);
        f4v acc = {0.f,0.f,0.f,0.f};
        const unsigned short* br = WqTb + (size_t)(n0 + m16)*256 + q16*8;
        #pragma unroll
        for (int i = 0; i < 8; ++i){
            s8v bb = *(const s8v*)(br + i*32);
            acc = __builtin_amdgcn_mfma_f32_16x16x32_bf16(a[i], bb, acc, 0, 0, 0);
        }
        #pragma unroll
        for (int r = 0; r < 4; ++r) xc[0][4*q16 + r][n0 + m16] = f2b(acc[r]);
    }
    __syncthreads();

    const float* cfp = coefb + (size_t)g*64 + sbase;   // zeros past nl (kcoef init)
    f4v hacc;
    for (int l = 0; l < 4; ++l){
        s8v xa[8];
        #pragma unroll
        for (int i = 0; i < 8; ++i)
            xa[i] = *(const s8v*)(&xc[l & 1][m16][q16*8 + i*32]);
        const unsigned short* Xl = Xb + ((size_t)l*128 + b*64 + sbase)*4096;
        const unsigned short* Gl = GT + ((size_t)l*128 + b*64 + sbase)*4096;
        // issue score X loads early (waves 0-7, one chunk each)
        s8v xr8[8]; float cf = 0.f;
        if (w < 8){
            cf = cfp[w];
            const unsigned short* Xr = Xl + (size_t)w*4096 + m16*256 + q16*8;
            #pragma unroll
            for (int i = 0; i < 8; ++i) xr8[i] = *(const s8v*)(Xr + i*32);
        }
        // issue PV G loads early (consumed after the barrier)
        h8 gpre[4];
        #pragma unroll
        for (int p = 0; p < 4; ++p)
            gpre[p] = ldh8(Gl + (size_t)(2*p + c01)*4096 + (size_t)(n0 + m16)*16 + koff);
        // dense: x @ (W + A*Ucp + B*Mcp)  (uniform path; seg==0 scales by 0)
        {
            const unsigned short* br = WTb + (size_t)l*DDn + (size_t)(n0 + m16)*256 + q16*8;
            size_t cko = ((size_t)(b*4 + l)*7 + segm1)*65536 + (size_t)(n0 + m16)*256 + q16*8;
            const unsigned short* bu = ucpb + cko;
            const unsigned short* bm = mcpb + cko;
            f4v aW = {0.f,0.f,0.f,0.f}, aU = {0.f,0.f,0.f,0.f}, aM = {0.f,0.f,0.f,0.f};
            #pragma unroll
            for (int i = 0; i < 8; ++i){
                s8v w0 = *(const s8v*)(br + i*32);
                s8v u0 = *(const s8v*)(bu + i*32);
                s8v m0 = *(const s8v*)(bm + i*32);
                aW = __builtin_amdgcn_mfma_f32_16x16x32_bf16(xa[i], w0, aW, 0, 0, 0);
                aU = __builtin_amdgcn_mfma_f32_16x16x32_bf16(xa[i], u0, aU, 0, 0, 0);
                aM = __builtin_amdgcn_mfma_f32_16x16x32_bf16(xa[i], m0, aM, 0, 0, 0);
            }
            #pragma unroll
            for (int r = 0; r < 4; ++r) hacc[r] = aW[r] + uaf*aU[r] + ubf*aM[r];
        }
        // scores (waves 0-7) -> ss
        if (w < 8){
            f4v st  = {0.f,0.f,0.f,0.f};
            f4v st2 = {0.f,0.f,0.f,0.f};
            #pragma unroll
            for (int i = 0; i < 8; i += 2){
                st  = __builtin_amdgcn_mfma_f32_16x16x32_bf16(xr8[i],   xa[i],   st,  0, 0, 0);
                st2 = __builtin_amdgcn_mfma_f32_16x16x32_bf16(xr8[i+1], xa[i+1], st2, 0, 0, 0);
            }
            h4 sv;
            #pragma unroll
            for (int r = 0; r < 4; ++r) sv[r] = (_Float16)((st[r] + st2[r])*cf);
            *(h4*)&ss[w][m16][q16*4] = sv;
        }
        __syncthreads();
        // PV: 4 chunk-pairs, K=32 f16 MFMA
        #pragma unroll
        for (int p = 0; p < 4; ++p){
            h8 sa = ldh8(&ss[2*p + c01][m16][koff]);
            hacc = __builtin_amdgcn_mfma_f32_16x16x32_f16(sa, gpre[p], hacc, 0, 0, 0);
        }
        if (l < 3){
            #pragma unroll
            for (int r = 0; r < 4; ++r)
                xc[(l + 1) & 1][4*q16 + r][n0 + m16] = f2b(silu_(hacc[r]));
        }
        __syncthreads();   // publishes xc for next layer; guards ss rewrite
    }

    // epilogue: post rmsnorm + shift + store
    float part[4];
    #pragma unroll
    for (int r = 0; r < 4; ++r) part[r] = hacc[r]*hacc[r];
    #pragma unroll
    for (int off = 1; off < 16; off <<= 1)
        #pragma unroll
        for (int r = 0; r < 4; ++r) part[r] += __shfl_xor(part[r], off, 64);
    if (m16 == 0)
        #pragma unroll
        for (int r = 0; r < 4; ++r) red[w][4*q16 + r] = part[r];
    __syncthreads();
    if (tid < 16){
        float s = 0.f;
        #pragma unroll
        for (int i = 0; i < 16; ++i) s += red[i][tid];
        rs[tid] = rsqrtf(s*(1.f/256.f) + EPSf);
    }
    __syncthreads();
    {
        int d = n0 + m16;
        float wp = wpost[d];
        #pragma unroll
        for (int r = 0; r < 4; ++r){
            int c = 4*q16 + r;
            int tp = nl*16 + c + 15;
            if (tp < 1024)
                out[((size_t)b*1024 + tp)*256 + d] = hacc[r]*rs[c]*wp;
        }
    }
    if (nl == 0){
        for (int idx = tid; idx < 15*256; idx += 1024)
            out[(size_t)b*262144 + idx] = 0.f;
    }
}

extern "C" void kernel_launch(void* const* d_in, const int* in_sizes, int n_in,
                              void* d_out, int out_size, void* d_ws, size_t ws_size,
                              hipStream_t stream) {
    const float* seq     = (const float*)d_in[0];
    const float* w_store = (const float*)d_in[1];
    const float* w_retr  = (const float*)d_in[2];
    const float* w_post  = (const float*)d_in[3];
    const float* Wq      = (const float*)d_in[4];
    const float* Wkv     = (const float*)d_in[5];
    const float* w_adapt = (const float*)d_in[6];
    const float* w_mom   = (const float*)d_in[7];
    const float* w_decay = (const float*)d_in[8];
    const float* W0      = (const float*)d_in[9];
    const float* W1      = (const float*)d_in[10];
    const float* W2      = (const float*)d_in[11];
    const float* W3      = (const float*)d_in[12];

    float* momg  = (float*)d_ws;                       // 128
    float* decg  = momg + NCn;                         // 128
    float* coefb = decg + NCn;                         // 8192
    float* mpb   = coefb + (size_t)NCn*64;             // 8192
    float* apg   = mpb + (size_t)NCn*64;               // 128
    float* bpg   = apg + NCn;                          // 128
    float* mpg   = bpg + NCn;                          // 128
    unsigned short* snb   = (unsigned short*)(mpg + NCn + 32);
    unsigned short* rnb   = snb   + (size_t)NCn*4096;
    unsigned short* WTb   = rnb   + (size_t)NCn*4096;
    unsigned short* Wb    = WTb   + 4*(size_t)DDn;
    unsigned short* WqTb  = Wb    + 3*(size_t)DDn;
    unsigned short* WkvTb = WqTb  + (size_t)DDn;
    unsigned short* Xb    = WkvTb + 2*(size_t)DDn;       // bf16 [l][g][c][d], 4 MB
    unsigned short* XT    = Xb    + (size_t)4*NCn*4096;  // f16  [l][g][d][c], 4 MB
    unsigned short* GT    = XT    + (size_t)4*NCn*4096;  // f16  [l][g][d][c], 4 MB
    unsigned short* ucpb  = GT    + (size_t)4*NCn*4096;  // bf16 [bl][7][256][256]
    unsigned short* mcpb  = ucpb  + (size_t)8*7*65536;   // bf16 [bl][7][256][256]

    ktw   <<<dim3(8, 16, 9), 256,  0, stream>>>(Wq, Wkv, W0, W1, W2, W3,
                                                WTb, WqTb, WkvTb, Wb);
    knorm <<<dim3(2048),     256,  0, stream>>>(seq, w_store, w_retr, snb, rnb);
    kfb   <<<dim3(NCn),      1024, 0, stream>>>(snb, WkvTb, WTb, Wb,
                                                w_adapt, w_mom, w_decay,
                                                momg, decg, Xb, XT, GT);
    kcoef <<<dim3(2),        64,   0, stream>>>(momg, decg, coefb, mpb, apg, bpg, mpg);
    kck   <<<dim3(16, 16, 8), 64,  0, stream>>>(XT, GT, coefb, mpb, apg, bpg, mpg,
                                                ucpb, mcpb);
    kretr <<<dim3(NCn),      1024, 0, stream>>>(rnb, WqTb, WTb, ucpb, mcpb, Xb, GT,
                                                coefb, apg, bpg, w_post, (float*)d_out);
}

// Round 10
// 177.383 us; speedup vs baseline: 3.1551x; 1.3174x over previous
//
#include <hip/hip_runtime.h>
#include <hip/hip_bf16.h>

typedef __attribute__((ext_vector_type(8)))  short s8v;   // 8 bf16
typedef __attribute__((ext_vector_type(4)))  float f4v;   // 16x16 C/D
typedef _Float16 h4 __attribute__((ext_vector_type(4)));  // 4 f16
typedef _Float16 h8 __attribute__((ext_vector_type(8)));  // 8 f16
typedef __attribute__((ext_vector_type(4))) unsigned short u4v;

constexpr int NCn  = 128;
constexpr int DDn  = 65536;
constexpr int XP   = 264;             // padded LDS row (bf16 elems)
constexpr int SSP  = 24;              // padded score row (f16 elems, 48B)
constexpr float EPSf = 1.1920929e-07f;

__device__ __forceinline__ float sigm(float x){ return 1.0f/(1.0f + expf(-x)); }
__device__ __forceinline__ float silu_(float x){ return x * sigm(x); }
__device__ __forceinline__ float dsilu_(float x){ float s = sigm(x); return s*(1.0f + x*(1.0f - s)); }

__device__ __forceinline__ unsigned short f2b(float x){
    __hip_bfloat16 b = __float2bfloat16(x);
    unsigned short u; __builtin_memcpy(&u, &b, 2); return u;
}
__device__ __forceinline__ float b2f(unsigned short u){
    __hip_bfloat16 b; __builtin_memcpy(&b, &u, 2); return __bfloat162float(b);
}
__device__ __forceinline__ h4 ldh4(const unsigned short* p){
    h4 r; __builtin_memcpy(&r, p, 8); return r;
}
__device__ __forceinline__ h8 ldh8(const void* p){
    h8 r; __builtin_memcpy(&r, p, 16); return r;
}

// fragment-order index: element (row, col) of a [R][256] matrix stored so that
// a wave's MFMA fragment load (tile=row>>4, i=col>>5, lane=(q16,m16), j) is a
// contiguous 1KB read:  addr = ((tile*8 + i)*4 + q16)*128 + m16*8 + j
__device__ __forceinline__ int fidx(int row, int col){
    return (((row >> 4)*8 + (col >> 5))*4 + ((col >> 3) & 3))*128 + (row & 15)*8 + (col & 7);
}

__device__ __forceinline__ float block_sum(float v, float* red){   // 256 thr
    #pragma unroll
    for (int off = 32; off; off >>= 1) v += __shfl_down(v, off, 64);
    if ((threadIdx.x & 63) == 0) red[threadIdx.x >> 6] = v;
    __syncthreads();
    float r = red[0] + red[1] + red[2] + red[3];
    __syncthreads();
    return r;
}

// ---- merged weight prep: z 0..5 tiled transpose fp32->bf16 frag-order,
//      z 6..8 cast-copy frag-order ----
__global__ __launch_bounds__(256) void ktw(const float* __restrict__ Wq,
        const float* __restrict__ Wkv, const float* __restrict__ W0,
        const float* __restrict__ W1, const float* __restrict__ W2,
        const float* __restrict__ W3, unsigned short* __restrict__ WTb,
        unsigned short* __restrict__ WqTb, unsigned short* __restrict__ WkvTb,
        unsigned short* __restrict__ Wb){
    int z = blockIdx.z;
    if (z >= 6){
        const float* S = (z==6)?W1:(z==7)?W2:W3;
        size_t idx = (((size_t)blockIdx.y*8 + blockIdx.x)*256 + threadIdx.x)*2;
        float2 v = *(const float2*)(S + idx);
        ushort2 u; u.x = f2b(v.x); u.y = f2b(v.y);
        int row = (int)(idx >> 8), col = (int)(idx & 255);
        *(ushort2*)(Wb + (size_t)(z-6)*DDn + fidx(row, col)) = u;
        return;
    }
    __shared__ float tl[32][33];
    if (z != 5 && blockIdx.y >= 8) return;
    const float* S; unsigned short* T; int C;
    if (z < 4){ S = (z==0)?W0:(z==1)?W1:(z==2)?W2:W3; T = WTb + (size_t)z*DDn; C = 256; }
    else if (z == 4){ S = Wq; T = WqTb; C = 256; }
    else { S = Wkv; T = WkvTb; C = 512; }
    int k0 = blockIdx.x*32, j0 = blockIdx.y*32;
    int tx = threadIdx.x & 31, ty = threadIdx.x >> 5;
    #pragma unroll
    for (int p = 0; p < 4; ++p)
        tl[ty + 8*p][tx] = S[(size_t)(k0 + ty + 8*p)*C + j0 + tx];
    __syncthreads();
    #pragma unroll
    for (int p = 0; p < 4; ++p){
        int r = j0 + ty + 8*p, k = k0 + tx;   // T[r][k] = S[k][r]
        T[fidx(r, k)] = f2b(tl[tx][ty + 8*p]);
    }
}

// ---- per-token norm: snb contiguous (gates) + snF frag (kfb) + rnF frag (kretr) ----
__global__ __launch_bounds__(256) void knorm(const float* __restrict__ seq,
        const float* __restrict__ wsn, const float* __restrict__ wrn,
        unsigned short* __restrict__ snb, unsigned short* __restrict__ snF,
        unsigned short* __restrict__ rnF){
    __shared__ float red[4];
    int t = blockIdx.x, d = threadIdx.x;
    int b = t >> 10, tl = t & 1023, g = t >> 4, c = tl & 15;
    float x = seq[(size_t)t*256 + d];
    float ss = block_sum(x*x, red);
    float xr = x * rsqrtf(ss*(1.f/256.f) + EPSf);
    unsigned short sv = f2b(xr*wsn[d]);
    snb[(size_t)g*4096 + c*256 + d] = sv;
    snF[(size_t)g*4096 + fidx(c, d)] = sv;
    if (tl >= 15){
        int tl2 = tl - 15, g2 = b*64 + (tl2 >> 4), c2 = tl2 & 15;
        rnF[(size_t)g2*4096 + fidx(c2, d)] = f2b(xr*wrn[d]);
    }
    if (tl >= 1009)
        rnF[(size_t)g*4096 + fidx(c, d)] = 0;
}

// ---- fwd + bwd dgrads + fused gates, one block per group, 16 waves ----
// all weight/activation frags read from fragment-order buffers (1KB contiguous/wave)
// writes XF bf16 frag-order, XT f16 [l][g][d][c], GT f16 [l][g][d][c]
__global__ __launch_bounds__(1024, 1) void kfb(const unsigned short* __restrict__ snb,
        const unsigned short* __restrict__ snF,
        const unsigned short* __restrict__ WkvTb, const unsigned short* __restrict__ WTb,
        const unsigned short* __restrict__ Wb,
        const float* __restrict__ wa, const float* __restrict__ wm,
        const float* __restrict__ wdk,
        float* __restrict__ momg, float* __restrict__ decg,
        unsigned short* __restrict__ XF, unsigned short* __restrict__ XT,
        unsigned short* __restrict__ GT){
    __shared__ unsigned short xl[4][16][XP];
    __shared__ unsigned short Gs[16][XP];
    __shared__ float red3[16][4];
    int tid = threadIdx.x, w = tid >> 6, lane = tid & 63;
    int m16 = lane & 15, q16 = lane >> 4;
    int g = blockIdx.x;
    int n0 = w*16;
    size_t fb = (size_t)w*4096 + q16*128 + m16*8;   // fragment base for rows n0..n0+15

    // issue A-frag loads early (hide under gate phase) — contiguous frag reads
    s8v af[8];
    const unsigned short* arow = snF + (size_t)g*4096 + q16*128 + m16*8;
    #pragma unroll
    for (int i = 0; i < 8; ++i) af[i] = *(const s8v*)(arow + i*512);

    float sc;
    {   // fused gates: one reduction pass, one barrier
        int d2 = tid & 255, qt = tid >> 8;
        float a = 0.f;
        #pragma unroll
        for (int c = 0; c < 4; ++c)
            a += b2f(snb[(size_t)g*4096 + (qt*4 + c)*256 + d2]);
        float cm = a * (1.f/16.f);
        float s0 = cm*wa[d2], s1 = cm*wm[d2], s2 = cm*wdk[d2];
        #pragma unroll
        for (int off = 32; off; off >>= 1){
            s0 += __shfl_down(s0, off, 64);
            s1 += __shfl_down(s1, off, 64);
            s2 += __shfl_down(s2, off, 64);
        }
        if (lane == 0){ red3[w][0] = s0; red3[w][1] = s1; red3[w][2] = s2; }
        __syncthreads();
        float da = 0.f, dm = 0.f, dc = 0.f;
        #pragma unroll
        for (int i = 0; i < 16; ++i){
            da += red3[i][0]; dm += red3[i][1]; dc += red3[i][2];
        }
        sc = -2.f * sigm(da) * (1.f/256.f);
        if (tid == 0){ momg[g] = sigm(dm); decg[g] = sigm(dc); }
    }

    // prefetch layer-0 weights (used after next barrier)
    s8v bpre[8];
    #pragma unroll
    for (int i = 0; i < 8; ++i) bpre[i] = *(const s8v*)(WTb + fb + i*512);

    f4v vacc;
    {
        f4v ka = {0.f,0.f,0.f,0.f}, va = {0.f,0.f,0.f,0.f};
        const unsigned short* brK = WkvTb + fb;            // K rows n0..
        const unsigned short* brV = WkvTb + (size_t)DDn + fb;   // V rows 256+n0..
        #pragma unroll
        for (int i = 0; i < 8; ++i){
            s8v bK = *(const s8v*)(brK + i*512);
            s8v bV = *(const s8v*)(brV + i*512);
            ka = __builtin_amdgcn_mfma_f32_16x16x32_bf16(af[i], bK, ka, 0, 0, 0);
            va = __builtin_amdgcn_mfma_f32_16x16x32_bf16(af[i], bV, va, 0, 0, 0);
        }
        vacc = va;
        #pragma unroll
        for (int r = 0; r < 4; ++r) xl[0][4*q16 + r][n0 + m16] = f2b(ka[r]);
    }

    f4v hreg[3];
    #pragma unroll
    for (int l = 0; l < 3; ++l){
        __syncthreads();
        s8v xa[8];
        #pragma unroll
        for (int i = 0; i < 8; ++i)
            xa[i] = *(const s8v*)(&xl[l][m16][q16*8 + i*32]);
        s8v bcur[8];
        #pragma unroll
        for (int i = 0; i < 8; ++i) bcur[i] = bpre[i];
        const unsigned short* nxt = WTb + (size_t)(l+1)*DDn + fb;
        #pragma unroll
        for (int i = 0; i < 8; ++i) bpre[i] = *(const s8v*)(nxt + i*512);
        f4v acc = {0.f,0.f,0.f,0.f};
        #pragma unroll
        for (int i = 0; i < 8; ++i)
            acc = __builtin_amdgcn_mfma_f32_16x16x32_bf16(xa[i], bcur[i], acc, 0, 0, 0);
        hreg[l] = acc;
        #pragma unroll
        for (int r = 0; r < 4; ++r)
            xl[l+1][4*q16 + r][n0 + m16] = f2b(silu_(acc[r]));
    }
    __syncthreads();

    {   // dump layer inputs XF frag-order (linear store: frag index == linear o)
        int o = tid*4;
        int oi = o >> 9, oq = (o >> 7) & 3, om = (o >> 3) & 15, oj = o & 7;
        int cbase = oi*32 + oq*8 + oj;
        #pragma unroll
        for (int l = 0; l < 4; ++l){
            u4v v;
            #pragma unroll
            for (int jj = 0; jj < 4; ++jj)
                v[jj] = xl[l][om][cbase + jj];
            *(u4v*)(XF + ((size_t)l*128 + g)*4096 + o) = v;
        }
    }
    {   // dump XT f16 [l][g][d][c]
        int d = tid & 255, qt = tid >> 8;
        #pragma unroll
        for (int l = 0; l < 4; ++l){
            h4 v;
            #pragma unroll
            for (int j = 0; j < 4; ++j)
                v[j] = (_Float16)b2f(xl[l][qt*4 + j][d]);
            *(h4*)(XT + (((size_t)l*128 + g)*256 + d)*16 + qt*4) = v;
        }
    }

    {   // layer 3 (pred) -> Gs; prefetch Wb[2] for bwd l=3
        s8v xa[8];
        #pragma unroll
        for (int i = 0; i < 8; ++i)
            xa[i] = *(const s8v*)(&xl[3][m16][q16*8 + i*32]);
        s8v bcur[8];
        #pragma unroll
        for (int i = 0; i < 8; ++i) bcur[i] = bpre[i];
        const unsigned short* nxt = Wb + (size_t)2*DDn + fb;
        #pragma unroll
        for (int i = 0; i < 8; ++i) bpre[i] = *(const s8v*)(nxt + i*512);
        f4v acc = {0.f,0.f,0.f,0.f};
        #pragma unroll
        for (int i = 0; i < 8; ++i)
            acc = __builtin_amdgcn_mfma_f32_16x16x32_bf16(xa[i], bcur[i], acc, 0, 0, 0);
        #pragma unroll
        for (int r = 0; r < 4; ++r)
            Gs[4*q16 + r][n0 + m16] = f2b(sc * (acc[r] - vacc[r]));
    }
    __syncthreads();
    {   // write f16 GT[3][g][d][c]
        int d = tid & 255, qt = tid >> 8;
        h4 v;
        #pragma unroll
        for (int j = 0; j < 4; ++j)
            v[j] = (_Float16)b2f(Gs[qt*4 + j][d]);
        *(h4*)(GT + (((size_t)3*128 + g)*256 + d)*16 + qt*4) = v;
    }

    #pragma unroll
    for (int l = 3; l >= 1; --l){
        s8v gfa[8];
        #pragma unroll
        for (int i = 0; i < 8; ++i)
            gfa[i] = *(const s8v*)(&Gs[m16][q16*8 + i*32]);
        s8v bcur[8];
        #pragma unroll
        for (int i = 0; i < 8; ++i) bcur[i] = bpre[i];
        if (l > 1){
            const unsigned short* nxt = Wb + (size_t)(l-2)*DDn + fb;
            #pragma unroll
            for (int i = 0; i < 8; ++i) bpre[i] = *(const s8v*)(nxt + i*512);
        }
        f4v acc = {0.f,0.f,0.f,0.f};
        #pragma unroll
        for (int i = 0; i < 8; ++i)
            acc = __builtin_amdgcn_mfma_f32_16x16x32_bf16(gfa[i], bcur[i], acc, 0, 0, 0);
        f4v gn;
        #pragma unroll
        for (int r = 0; r < 4; ++r)
            gn[r] = acc[r] * dsilu_(hreg[l-1][r]);
        __syncthreads();
        #pragma unroll
        for (int r = 0; r < 4; ++r)
            Gs[4*q16 + r][n0 + m16] = f2b(gn[r]);
        __syncthreads();
        {
            int d = tid & 255, qt = tid >> 8;
            h4 v;
            #pragma unroll
            for (int j = 0; j < 4; ++j)
                v[j] = (_Float16)b2f(Gs[qt*4 + j][d]);
            *(h4*)(GT + (((size_t)(l-1)*128 + g)*256 + d)*16 + qt*4) = v;
        }
    }
}

// ---- coefficients: cf(g,n), mp(g,n), and per-g segment scalars A_g,B_g,PImo_g ----
__global__ __launch_bounds__(64) void kcoef(const float* __restrict__ momg,
        const float* __restrict__ decg, float* __restrict__ coefb,
        float* __restrict__ mpb, float* __restrict__ apg,
        float* __restrict__ bpg, float* __restrict__ mpg){
    int b = blockIdx.x, n = threadIdx.x;
    float M = 0.f, cf = 0.f;
    for (int gg = 0; gg < 64; ++gg){
        float mo = momg[b*64 + gg], de = 1.f - decg[b*64 + gg];
        if (gg == n){ M = 1.f; cf = 1.f; }
        else if (gg > n){ M *= mo; cf = de*cf + M; }
        coefb[((size_t)b*64 + gg)*64 + n] = cf;
        mpb  [((size_t)b*64 + gg)*64 + n] = M;
    }
    int ss0 = n & ~7;
    float a = 1.f, B = 0.f, pm = 1.f;
    for (int j = ss0; j <= n; ++j){
        float mo = momg[b*64 + j], de = 1.f - decg[b*64 + j];
        pm *= mo; B = de*B + pm; a *= de;
    }
    apg[b*64 + n] = a; bpg[b*64 + n] = B; mpg[b*64 + n] = pm;
}

// ---- fused segment partials + scan -> bf16 checkpoints (frag-order output) ----
// grid (16 rowtiles, 16 coltiles, 8 bl), 1 wave/block; scan state = 8 VGPR
__global__ __launch_bounds__(64, 1) void kck(const unsigned short* __restrict__ XT,
        const unsigned short* __restrict__ GT, const float* __restrict__ coefb,
        const float* __restrict__ mpb, const float* __restrict__ apg,
        const float* __restrict__ bpg, const float* __restrict__ mpg,
        unsigned short* __restrict__ ucpb, unsigned short* __restrict__ mcpb){
    int lane = threadIdx.x;
    int m16 = lane & 15, q16 = lane >> 4;
    int rt = blockIdx.x, ct = blockIdx.y, bl = blockIdx.z;
    int b = bl >> 2, l = bl & 3;
    int dr = rt*16 + m16;   // G row (dout)
    int dc = ct*16 + m16;   // X row (din)
    const unsigned short* Gb = GT + ((size_t)l*128 + b*64)*4096 + (size_t)dr*16 + q16*4;
    const unsigned short* Xb2 = XT + ((size_t)l*128 + b*64)*4096 + (size_t)dc*16 + q16*4;
    // frag-order write base: element (row = rt*16 + 4*q16 + r, col = ct*16 + m16)
    int col = ct*16 + m16;
    int fo0 = ((rt*8 + (col >> 5))*4 + ((col >> 3) & 3))*128 + (4*q16)*8 + (col & 7);
    f4v us = {0.f,0.f,0.f,0.f}, ms = {0.f,0.f,0.f,0.f};
    for (int s = 0; s < 7; ++s){
        int e = b*64 + s*8 + 7;
        float av = apg[e], bv = bpg[e], mv = mpg[e];
        const float* cfr = coefb + (size_t)e*64 + s*8;
        const float* mpr = mpb   + (size_t)e*64 + s*8;
        f4v acu = {0.f,0.f,0.f,0.f}, acm = {0.f,0.f,0.f,0.f};
        #pragma unroll
        for (int n = 0; n < 8; ++n){
            h4 a  = ldh4(Gb  + (size_t)(s*8 + n)*4096);
            h4 xb = ldh4(Xb2 + (size_t)(s*8 + n)*4096);
            _Float16 cfh = (_Float16)cfr[n];
            _Float16 mph = (_Float16)mpr[n];
            acu = __builtin_amdgcn_mfma_f32_16x16x16f16(a*cfh, xb, acu, 0, 0, 0);
            acm = __builtin_amdgcn_mfma_f32_16x16x16f16(a*mph, xb, acm, 0, 0, 0);
        }
        size_t cb = ((size_t)bl*7 + s)*65536;
        #pragma unroll
        for (int r = 0; r < 4; ++r){
            float un = av*us[r] + bv*ms[r] + acu[r];
            float mn = mv*ms[r] + acm[r];
            us[r] = un; ms[r] = mn;
            ucpb[cb + fo0 + r*8] = f2b(un);
            mcpb[cb + fo0 + r*8] = f2b(mn);
        }
    }
}

// ---- retrieval: q-proj + 4 layers {x@(W + A*Ucp + B*Mcp) + <=8 local chunks} ----
// 16 waves; all fragment loads contiguous 1KB/wave; LDS score staging; 2 barriers/layer
__global__ __launch_bounds__(1024, 1) void kretr(const unsigned short* __restrict__ rnF,
        const unsigned short* __restrict__ WqTb, const unsigned short* __restrict__ WTb,
        const unsigned short* __restrict__ ucpb, const unsigned short* __restrict__ mcpb,
        const unsigned short* __restrict__ XF, const unsigned short* __restrict__ GT,
        const float* __restrict__ coefb, const float* __restrict__ apg,
        const float* __restrict__ bpg, const float* __restrict__ wpost,
        float* __restrict__ out){
    __shared__ unsigned short xc[2][16][XP];
    __shared__ _Float16 ss[8][16][SSP];   // [local chunk][j][i]
    __shared__ float red[16][16];
    __shared__ float rs[16];
    int tid = threadIdx.x, w = tid >> 6, lane = tid & 63;
    int m16 = lane & 15, q16 = lane >> 4;
    // XCD swizzle: co-locate the 8 blocks sharing a (b,seg) checkpoint on one XCD
    int B = blockIdx.x;
    int g = (((B & 7)*2) + ((B >> 3) & 1))*8 + (B >> 4);
    int b = g >> 6, nl = g & 63;
    int seg = nl >> 3, sbase = seg*8;
    int segm1 = seg ? seg - 1 : 0;
    float uaf = seg ? apg[g] : 0.f;
    float ubf = seg ? bpg[g] : 0.f;
    int n0 = w*16;
    int c01 = q16 >> 1, koff = (q16 & 1)*8;   // PV pair decomposition
    size_t fb = (size_t)w*4096 + q16*128 + m16*8;   // fragment base (rows n0..n0+15)
    size_t afb = (size_t)q16*128 + m16*8;           // A-frag base (rows 0..15)

    {   // q-projection
        s8v a[8];
        const unsigned short* ar = rnF + (size_t)g*4096 + afb;
        #pragma unroll
        for (int i = 0; i < 8; ++i) a[i] = *(const s8v*)(ar + i*512);
        f4v acc = {0.f,0.f,0.f,0.f};
        const unsigned short* br = WqTb + fb;
        #pragma unroll
        for (int i = 0; i < 8; ++i){
            s8v bb = *(const s8v*)(br + i*512);
            acc = __builtin_amdgcn_mfma_f32_16x16x32_bf16(a[i], bb, acc, 0, 0, 0);
        }
        #pragma unroll
        for (int r = 0; r < 4; ++r) xc[0][4*q16 + r][n0 + m16] = f2b(acc[r]);
    }
    __syncthreads();

    const float* cfp = coefb + (size_t)g*64 + sbase;   // zeros past nl (kcoef init)
    f4v hacc;
    for (int l = 0; l < 4; ++l){
        s8v xa[8];
        #pragma unroll
        for (int i = 0; i < 8; ++i)
            xa[i] = *(const s8v*)(&xc[l & 1][m16][q16*8 + i*32]);
        const unsigned short* Gl = GT + ((size_t)l*128 + b*64 + sbase)*4096;
        // issue score X loads early (waves 0-7, one chunk each) — contiguous frags
        s8v xr8[8]; float cf = 0.f;
        if (w < 8){
            cf = cfp[w];
            const unsigned short* Xr = XF + ((size_t)l*128 + b*64 + sbase + w)*4096 + afb;
            #pragma unroll
            for (int i = 0; i < 8; ++i) xr8[i] = *(const s8v*)(Xr + i*512);
        }
        // issue PV G loads early (consumed after the barrier)
        h8 gpre[4];
        #pragma unroll
        for (int p = 0; p < 4; ++p)
            gpre[p] = ldh8(Gl + (size_t)(2*p + c01)*4096 + (size_t)(n0 + m16)*16 + koff);
        // dense: x @ (W + A*Ucp + B*Mcp)  (uniform path; seg==0 scales by 0)
        {
            const unsigned short* br = WTb + (size_t)l*DDn + fb;
            size_t cko = ((size_t)(b*4 + l)*7 + segm1)*65536 + fb;
            const unsigned short* bu = ucpb + cko;
            const unsigned short* bm = mcpb + cko;
            f4v aW = {0.f,0.f,0.f,0.f}, aU = {0.f,0.f,0.f,0.f}, aM = {0.f,0.f,0.f,0.f};
            #pragma unroll
            for (int i = 0; i < 8; ++i){
                s8v w0 = *(const s8v*)(br + i*512);
                s8v u0 = *(const s8v*)(bu + i*512);
                s8v m0 = *(const s8v*)(bm + i*512);
                aW = __builtin_amdgcn_mfma_f32_16x16x32_bf16(xa[i], w0, aW, 0, 0, 0);
                aU = __builtin_amdgcn_mfma_f32_16x16x32_bf16(xa[i], u0, aU, 0, 0, 0);
                aM = __builtin_amdgcn_mfma_f32_16x16x32_bf16(xa[i], m0, aM, 0, 0, 0);
            }
            #pragma unroll
            for (int r = 0; r < 4; ++r) hacc[r] = aW[r] + uaf*aU[r] + ubf*aM[r];
        }
        // scores (waves 0-7) -> ss
        if (w < 8){
            f4v st  = {0.f,0.f,0.f,0.f};
            f4v st2 = {0.f,0.f,0.f,0.f};
            #pragma unroll
            for (int i = 0; i < 8; i += 2){
                st  = __builtin_amdgcn_mfma_f32_16x16x32_bf16(xr8[i],   xa[i],   st,  0, 0, 0);
                st2 = __builtin_amdgcn_mfma_f32_16x16x32_bf16(xr8[i+1], xa[i+1], st2, 0, 0, 0);
            }
            h4 sv;
            #pragma unroll
            for (int r = 0; r < 4; ++r) sv[r] = (_Float16)((st[r] + st2[r])*cf);
            *(h4*)&ss[w][m16][q16*4] = sv;
        }
        __syncthreads();
        // PV: 4 chunk-pairs, K=32 f16 MFMA
        #pragma unroll
        for (int p = 0; p < 4; ++p){
            h8 sa = ldh8(&ss[2*p + c01][m16][koff]);
            hacc = __builtin_amdgcn_mfma_f32_16x16x32_f16(sa, gpre[p], hacc, 0, 0, 0);
        }
        if (l < 3){
            #pragma unroll
            for (int r = 0; r < 4; ++r)
                xc[(l + 1) & 1][4*q16 + r][n0 + m16] = f2b(silu_(hacc[r]));
        }
        __syncthreads();   // publishes xc for next layer; guards ss rewrite
    }

    // epilogue: post rmsnorm + shift + store
    float part[4];
    #pragma unroll
    for (int r = 0; r < 4; ++r) part[r] = hacc[r]*hacc[r];
    #pragma unroll
    for (int off = 1; off < 16; off <<= 1)
        #pragma unroll
        for (int r = 0; r < 4; ++r) part[r] += __shfl_xor(part[r], off, 64);
    if (m16 == 0)
        #pragma unroll
        for (int r = 0; r < 4; ++r) red[w][4*q16 + r] = part[r];
    __syncthreads();
    if (tid < 16){
        float s = 0.f;
        #pragma unroll
        for (int i = 0; i < 16; ++i) s += red[i][tid];
        rs[tid] = rsqrtf(s*(1.f/256.f) + EPSf);
    }
    __syncthreads();
    {
        int d = n0 + m16;
        float wp = wpost[d];
        #pragma unroll
        for (int r = 0; r < 4; ++r){
            int c = 4*q16 + r;
            int tp = nl*16 + c + 15;
            if (tp < 1024)
                out[((size_t)b*1024 + tp)*256 + d] = hacc[r]*rs[c]*wp;
        }
    }
    if (nl == 0){
        for (int idx = tid; idx < 15*256; idx += 1024)
            out[(size_t)b*262144 + idx] = 0.f;
    }
}

extern "C" void kernel_launch(void* const* d_in, const int* in_sizes, int n_in,
                              void* d_out, int out_size, void* d_ws, size_t ws_size,
                              hipStream_t stream) {
    const float* seq     = (const float*)d_in[0];
    const float* w_store = (const float*)d_in[1];
    const float* w_retr  = (const float*)d_in[2];
    const float* w_post  = (const float*)d_in[3];
    const float* Wq      = (const float*)d_in[4];
    const float* Wkv     = (const float*)d_in[5];
    const float* w_adapt = (const float*)d_in[6];
    const float* w_mom   = (const float*)d_in[7];
    const float* w_decay = (const float*)d_in[8];
    const float* W0      = (const float*)d_in[9];
    const float* W1      = (const float*)d_in[10];
    const float* W2      = (const float*)d_in[11];
    const float* W3      = (const float*)d_in[12];

    float* momg  = (float*)d_ws;                       // 128
    float* decg  = momg + NCn;                         // 128
    float* coefb = decg + NCn;                         // 8192
    float* mpb   = coefb + (size_t)NCn*64;             // 8192
    float* apg   = mpb + (size_t)NCn*64;               // 128
    float* bpg   = apg + NCn;                          // 128
    float* mpg   = bpg + NCn;                          // 128
    unsigned short* snb   = (unsigned short*)(mpg + NCn + 32);
    unsigned short* snF   = snb   + (size_t)NCn*4096;
    unsigned short* rnF   = snF   + (size_t)NCn*4096;
    unsigned short* WTb   = rnF   + (size_t)NCn*4096;
    unsigned short* Wb    = WTb   + 4*(size_t)DDn;
    unsigned short* WqTb  = Wb    + 3*(size_t)DDn;
    unsigned short* WkvTb = WqTb  + (size_t)DDn;
    unsigned short* XF    = WkvTb + 2*(size_t)DDn;       // bf16 frag-order, 4 MB
    unsigned short* XT    = XF    + (size_t)4*NCn*4096;  // f16  [l][g][d][c], 4 MB
    unsigned short* GT    = XT    + (size_t)4*NCn*4096;  // f16  [l][g][d][c], 4 MB
    unsigned short* ucpb  = GT    + (size_t)4*NCn*4096;  // bf16 frag-order ckpts
    unsigned short* mcpb  = ucpb  + (size_t)8*7*65536;   // bf16 frag-order ckpts

    ktw   <<<dim3(8, 16, 9), 256,  0, stream>>>(Wq, Wkv, W0, W1, W2, W3,
                                                WTb, WqTb, WkvTb, Wb);
    knorm <<<dim3(2048),     256,  0, stream>>>(seq, w_store, w_retr, snb, snF, rnF);
    kfb   <<<dim3(NCn),      1024, 0, stream>>>(snb, snF, WkvTb, WTb, Wb,
                                                w_adapt, w_mom, w_decay,
                                                momg, decg, XF, XT, GT);
    kcoef <<<dim3(2),        64,   0, stream>>>(momg, decg, coefb, mpb, apg, bpg, mpg);
    kck   <<<dim3(16, 16, 8), 64,  0, stream>>>(XT, GT, coefb, mpb, apg, bpg, mpg,
                                                ucpb, mcpb);
    kretr <<<dim3(NCn),      1024, 0, stream>>>(rnF, WqTb, WTb, ucpb, mcpb, XF, GT,
                                                coefb, apg, bpg, w_post, (float*)d_out);
}

// Round 11
// 147.163 us; speedup vs baseline: 3.8030x; 1.2054x over previous
//
#include <hip/hip_runtime.h>
#include <hip/hip_bf16.h>

typedef __attribute__((ext_vector_type(8)))  short s8v;   // 8 bf16
typedef __attribute__((ext_vector_type(4)))  float f4v;   // 16x16 C/D
typedef _Float16 h4 __attribute__((ext_vector_type(4)));  // 4 f16
typedef __attribute__((ext_vector_type(4))) unsigned short u4v;

constexpr int NCn  = 128;
constexpr int DDn  = 65536;
constexpr int XP   = 264;             // padded LDS row (bf16 elems)
constexpr float EPSf = 1.1920929e-07f;

__device__ __forceinline__ float sigm(float x){ return 1.0f/(1.0f + expf(-x)); }
__device__ __forceinline__ float silu_(float x){ return x * sigm(x); }
__device__ __forceinline__ float dsilu_(float x){ float s = sigm(x); return s*(1.0f + x*(1.0f - s)); }

__device__ __forceinline__ unsigned short f2b(float x){
    __hip_bfloat16 b = __float2bfloat16(x);
    unsigned short u; __builtin_memcpy(&u, &b, 2); return u;
}
__device__ __forceinline__ float b2f(unsigned short u){
    __hip_bfloat16 b; __builtin_memcpy(&b, &u, 2); return __bfloat162float(b);
}
__device__ __forceinline__ h4 ldh4(const unsigned short* p){
    h4 r; __builtin_memcpy(&r, p, 8); return r;
}

// fragment-order index: element (row, col) of a [R][256] matrix stored so that
// a wave's MFMA fragment load (tile=row>>4, i=col>>5, lane=(q16,m16), j) is a
// contiguous 1KB read:  addr = ((tile*8 + i)*4 + q16)*128 + m16*8 + j
__device__ __forceinline__ int fidx(int row, int col){
    return (((row >> 4)*8 + (col >> 5))*4 + ((col >> 3) & 3))*128 + (row & 15)*8 + (col & 7);
}

__device__ __forceinline__ float block_sum(float v, float* red){   // 256 thr
    #pragma unroll
    for (int off = 32; off; off >>= 1) v += __shfl_down(v, off, 64);
    if ((threadIdx.x & 63) == 0) red[threadIdx.x >> 6] = v;
    __syncthreads();
    float r = red[0] + red[1] + red[2] + red[3];
    __syncthreads();
    return r;
}

// ---- merged weight prep: z 0..5 tiled transpose fp32->bf16 frag-order,
//      z 6..8 cast-copy frag-order ----
__global__ __launch_bounds__(256) void ktw(const float* __restrict__ Wq,
        const float* __restrict__ Wkv, const float* __restrict__ W0,
        const float* __restrict__ W1, const float* __restrict__ W2,
        const float* __restrict__ W3, unsigned short* __restrict__ WTb,
        unsigned short* __restrict__ WqTb, unsigned short* __restrict__ WkvTb,
        unsigned short* __restrict__ Wb){
    int z = blockIdx.z;
    if (z >= 6){
        const float* S = (z==6)?W1:(z==7)?W2:W3;
        size_t idx = (((size_t)blockIdx.y*8 + blockIdx.x)*256 + threadIdx.x)*2;
        float2 v = *(const float2*)(S + idx);
        ushort2 u; u.x = f2b(v.x); u.y = f2b(v.y);
        int row = (int)(idx >> 8), col = (int)(idx & 255);
        *(ushort2*)(Wb + (size_t)(z-6)*DDn + fidx(row, col)) = u;
        return;
    }
    __shared__ float tl[32][33];
    if (z != 5 && blockIdx.y >= 8) return;
    const float* S; unsigned short* T; int C;
    if (z < 4){ S = (z==0)?W0:(z==1)?W1:(z==2)?W2:W3; T = WTb + (size_t)z*DDn; C = 256; }
    else if (z == 4){ S = Wq; T = WqTb; C = 256; }
    else { S = Wkv; T = WkvTb; C = 512; }
    int k0 = blockIdx.x*32, j0 = blockIdx.y*32;
    int tx = threadIdx.x & 31, ty = threadIdx.x >> 5;
    #pragma unroll
    for (int p = 0; p < 4; ++p)
        tl[ty + 8*p][tx] = S[(size_t)(k0 + ty + 8*p)*C + j0 + tx];
    __syncthreads();
    #pragma unroll
    for (int p = 0; p < 4; ++p){
        int r = j0 + ty + 8*p, k = k0 + tx;   // T[r][k] = S[k][r]
        T[fidx(r, k)] = f2b(tl[tx][ty + 8*p]);
    }
}

// ---- per-token norm: snb contiguous (gates) + snF frag (kfb) + rnF frag (kretr) ----
__global__ __launch_bounds__(256) void knorm(const float* __restrict__ seq,
        const float* __restrict__ wsn, const float* __restrict__ wrn,
        unsigned short* __restrict__ snb, unsigned short* __restrict__ snF,
        unsigned short* __restrict__ rnF){
    __shared__ float red[4];
    int t = blockIdx.x, d = threadIdx.x;
    int b = t >> 10, tl = t & 1023, g = t >> 4, c = tl & 15;
    float x = seq[(size_t)t*256 + d];
    float ss = block_sum(x*x, red);
    float xr = x * rsqrtf(ss*(1.f/256.f) + EPSf);
    unsigned short sv = f2b(xr*wsn[d]);
    snb[(size_t)g*4096 + c*256 + d] = sv;
    snF[(size_t)g*4096 + fidx(c, d)] = sv;
    if (tl >= 15){
        int tl2 = tl - 15, g2 = b*64 + (tl2 >> 4), c2 = tl2 & 15;
        rnF[(size_t)g2*4096 + fidx(c2, d)] = f2b(xr*wrn[d]);
    }
    if (tl >= 1009)
        rnF[(size_t)g*4096 + fidx(c, d)] = 0;
}

// ---- fwd + bwd dgrads + fused gates, one block per group, 16 waves ----
// all weight/activation frags read from fragment-order buffers (1KB contiguous/wave)
// writes XT f16 [l][g][d][c], GT f16 [l][g][d][c]
__global__ __launch_bounds__(1024, 1) void kfb(const unsigned short* __restrict__ snb,
        const unsigned short* __restrict__ snF,
        const unsigned short* __restrict__ WkvTb, const unsigned short* __restrict__ WTb,
        const unsigned short* __restrict__ Wb,
        const float* __restrict__ wa, const float* __restrict__ wm,
        const float* __restrict__ wdk,
        float* __restrict__ momg, float* __restrict__ decg,
        unsigned short* __restrict__ XT, unsigned short* __restrict__ GT){
    __shared__ unsigned short xl[4][16][XP];
    __shared__ unsigned short Gs[16][XP];
    __shared__ float red3[16][4];
    int tid = threadIdx.x, w = tid >> 6, lane = tid & 63;
    int m16 = lane & 15, q16 = lane >> 4;
    int g = blockIdx.x;
    int n0 = w*16;
    size_t fb = (size_t)w*4096 + q16*128 + m16*8;   // fragment base for rows n0..n0+15

    // issue A-frag loads early (hide under gate phase) — contiguous frag reads
    s8v af[8];
    const unsigned short* arow = snF + (size_t)g*4096 + q16*128 + m16*8;
    #pragma unroll
    for (int i = 0; i < 8; ++i) af[i] = *(const s8v*)(arow + i*512);

    float sc;
    {   // fused gates: one reduction pass, one barrier
        int d2 = tid & 255, qt = tid >> 8;
        float a = 0.f;
        #pragma unroll
        for (int c = 0; c < 4; ++c)
            a += b2f(snb[(size_t)g*4096 + (qt*4 + c)*256 + d2]);
        float cm = a * (1.f/16.f);
        float s0 = cm*wa[d2], s1 = cm*wm[d2], s2 = cm*wdk[d2];
        #pragma unroll
        for (int off = 32; off; off >>= 1){
            s0 += __shfl_down(s0, off, 64);
            s1 += __shfl_down(s1, off, 64);
            s2 += __shfl_down(s2, off, 64);
        }
        if (lane == 0){ red3[w][0] = s0; red3[w][1] = s1; red3[w][2] = s2; }
        __syncthreads();
        float da = 0.f, dm = 0.f, dc = 0.f;
        #pragma unroll
        for (int i = 0; i < 16; ++i){
            da += red3[i][0]; dm += red3[i][1]; dc += red3[i][2];
        }
        sc = -2.f * sigm(da) * (1.f/256.f);
        if (tid == 0){ momg[g] = sigm(dm); decg[g] = sigm(dc); }
    }

    // prefetch layer-0 weights (used after next barrier)
    s8v bpre[8];
    #pragma unroll
    for (int i = 0; i < 8; ++i) bpre[i] = *(const s8v*)(WTb + fb + i*512);

    f4v vacc;
    {
        f4v ka = {0.f,0.f,0.f,0.f}, va = {0.f,0.f,0.f,0.f};
        const unsigned short* brK = WkvTb + fb;                 // K rows n0..
        const unsigned short* brV = WkvTb + (size_t)DDn + fb;   // V rows 256+n0..
        #pragma unroll
        for (int i = 0; i < 8; ++i){
            s8v bK = *(const s8v*)(brK + i*512);
            s8v bV = *(const s8v*)(brV + i*512);
            ka = __builtin_amdgcn_mfma_f32_16x16x32_bf16(af[i], bK, ka, 0, 0, 0);
            va = __builtin_amdgcn_mfma_f32_16x16x32_bf16(af[i], bV, va, 0, 0, 0);
        }
        vacc = va;
        #pragma unroll
        for (int r = 0; r < 4; ++r) xl[0][4*q16 + r][n0 + m16] = f2b(ka[r]);
    }

    f4v hreg[3];
    #pragma unroll
    for (int l = 0; l < 3; ++l){
        __syncthreads();
        s8v xa[8];
        #pragma unroll
        for (int i = 0; i < 8; ++i)
            xa[i] = *(const s8v*)(&xl[l][m16][q16*8 + i*32]);
        s8v bcur[8];
        #pragma unroll
        for (int i = 0; i < 8; ++i) bcur[i] = bpre[i];
        const unsigned short* nxt = WTb + (size_t)(l+1)*DDn + fb;
        #pragma unroll
        for (int i = 0; i < 8; ++i) bpre[i] = *(const s8v*)(nxt + i*512);
        f4v acc = {0.f,0.f,0.f,0.f};
        #pragma unroll
        for (int i = 0; i < 8; ++i)
            acc = __builtin_amdgcn_mfma_f32_16x16x32_bf16(xa[i], bcur[i], acc, 0, 0, 0);
        hreg[l] = acc;
        #pragma unroll
        for (int r = 0; r < 4; ++r)
            xl[l+1][4*q16 + r][n0 + m16] = f2b(silu_(acc[r]));
    }
    __syncthreads();

    {   // dump XT f16 [l][g][d][c]
        int d = tid & 255, qt = tid >> 8;
        #pragma unroll
        for (int l = 0; l < 4; ++l){
            h4 v;
            #pragma unroll
            for (int j = 0; j < 4; ++j)
                v[j] = (_Float16)b2f(xl[l][qt*4 + j][d]);
            *(h4*)(XT + (((size_t)l*128 + g)*256 + d)*16 + qt*4) = v;
        }
    }

    {   // layer 3 (pred) -> Gs; prefetch Wb[2] for bwd l=3
        s8v xa[8];
        #pragma unroll
        for (int i = 0; i < 8; ++i)
            xa[i] = *(const s8v*)(&xl[3][m16][q16*8 + i*32]);
        s8v bcur[8];
        #pragma unroll
        for (int i = 0; i < 8; ++i) bcur[i] = bpre[i];
        const unsigned short* nxt = Wb + (size_t)2*DDn + fb;
        #pragma unroll
        for (int i = 0; i < 8; ++i) bpre[i] = *(const s8v*)(nxt + i*512);
        f4v acc = {0.f,0.f,0.f,0.f};
        #pragma unroll
        for (int i = 0; i < 8; ++i)
            acc = __builtin_amdgcn_mfma_f32_16x16x32_bf16(xa[i], bcur[i], acc, 0, 0, 0);
        #pragma unroll
        for (int r = 0; r < 4; ++r)
            Gs[4*q16 + r][n0 + m16] = f2b(sc * (acc[r] - vacc[r]));
    }
    __syncthreads();
    {   // write f16 GT[3][g][d][c]
        int d = tid & 255, qt = tid >> 8;
        h4 v;
        #pragma unroll
        for (int j = 0; j < 4; ++j)
            v[j] = (_Float16)b2f(Gs[qt*4 + j][d]);
        *(h4*)(GT + (((size_t)3*128 + g)*256 + d)*16 + qt*4) = v;
    }

    #pragma unroll
    for (int l = 3; l >= 1; --l){
        s8v gfa[8];
        #pragma unroll
        for (int i = 0; i < 8; ++i)
            gfa[i] = *(const s8v*)(&Gs[m16][q16*8 + i*32]);
        s8v bcur[8];
        #pragma unroll
        for (int i = 0; i < 8; ++i) bcur[i] = bpre[i];
        if (l > 1){
            const unsigned short* nxt = Wb + (size_t)(l-2)*DDn + fb;
            #pragma unroll
            for (int i = 0; i < 8; ++i) bpre[i] = *(const s8v*)(nxt + i*512);
        }
        f4v acc = {0.f,0.f,0.f,0.f};
        #pragma unroll
        for (int i = 0; i < 8; ++i)
            acc = __builtin_amdgcn_mfma_f32_16x16x32_bf16(gfa[i], bcur[i], acc, 0, 0, 0);
        f4v gn;
        #pragma unroll
        for (int r = 0; r < 4; ++r)
            gn[r] = acc[r] * dsilu_(hreg[l-1][r]);
        __syncthreads();
        #pragma unroll
        for (int r = 0; r < 4; ++r)
            Gs[4*q16 + r][n0 + m16] = f2b(gn[r]);
        __syncthreads();
        {
            int d = tid & 255, qt = tid >> 8;
            h4 v;
            #pragma unroll
            for (int j = 0; j < 4; ++j)
                v[j] = (_Float16)b2f(Gs[qt*4 + j][d]);
            *(h4*)(GT + (((size_t)(l-1)*128 + g)*256 + d)*16 + qt*4) = v;
        }
    }
}

// ---- per-chunk update scan -> bf16 U_g checkpoints (frag-order) ----
// grid (16 rowtiles, 16 coltiles, 8 bl), 1 wave/block; exact reference recurrence:
//   S_g = X_g^T G_g ; m = mo_g*m + S_g ; u = (1-dec_g)*u + m ; store u (bf16)
__global__ __launch_bounds__(64, 1) void kck(const unsigned short* __restrict__ XT,
        const unsigned short* __restrict__ GT, const float* __restrict__ momg,
        const float* __restrict__ decg, unsigned short* __restrict__ ucpb){
    int lane = threadIdx.x;
    int m16 = lane & 15, q16 = lane >> 4;
    int rt = blockIdx.x, ct = blockIdx.y, bl = blockIdx.z;
    int b = bl >> 2, l = bl & 3;
    int dr = rt*16 + m16;   // G row (dout)
    int dc = ct*16 + m16;   // X row (din)
    const unsigned short* Gb  = GT + ((size_t)l*128 + b*64)*4096 + (size_t)dr*16 + q16*4;
    const unsigned short* Xb2 = XT + ((size_t)l*128 + b*64)*4096 + (size_t)dc*16 + q16*4;
    // frag-order write base: element (row = rt*16 + 4*q16 + r, col = ct*16 + m16)
    int col = ct*16 + m16;
    int fo0 = ((rt*8 + (col >> 5))*4 + ((col >> 3) & 3))*128 + (4*q16)*8 + (col & 7);
    f4v us = {0.f,0.f,0.f,0.f}, ms = {0.f,0.f,0.f,0.f};
    #pragma unroll 4
    for (int n = 0; n < 64; ++n){
        float mo = momg[b*64 + n], de = 1.f - decg[b*64 + n];
        h4 a  = ldh4(Gb  + (size_t)n*4096);
        h4 xb = ldh4(Xb2 + (size_t)n*4096);
        f4v z = {0.f,0.f,0.f,0.f};
        f4v s = __builtin_amdgcn_mfma_f32_16x16x16f16(a, xb, z, 0, 0, 0);
        size_t cb = ((size_t)bl*64 + n)*65536;
        #pragma unroll
        for (int r = 0; r < 4; ++r){
            float mn = mo*ms[r] + s[r];
            float un = de*us[r] + mn;
            ms[r] = mn; us[r] = un;
            ucpb[cb + fo0 + r*8] = f2b(un);
        }
    }
}

// ---- retrieval: q-proj + 4 layers { x @ (W_l + U_g) }, per-chunk checkpoints ----
// 16 waves; all fragment loads contiguous 1KB/wave; 1 barrier/layer; no flash part
__global__ __launch_bounds__(1024, 1) void kretr(const unsigned short* __restrict__ rnF,
        const unsigned short* __restrict__ WqTb, const unsigned short* __restrict__ WTb,
        const unsigned short* __restrict__ ucpb, const float* __restrict__ wpost,
        float* __restrict__ out){
    __shared__ unsigned short xc[2][16][XP];
    __shared__ float red[16][16];
    __shared__ float rs[16];
    int tid = threadIdx.x, w = tid >> 6, lane = tid & 63;
    int m16 = lane & 15, q16 = lane >> 4;
    int g = blockIdx.x;
    int b = g >> 6, nl = g & 63;
    int n0 = w*16;
    size_t fb = (size_t)w*4096 + q16*128 + m16*8;   // fragment base (rows n0..n0+15)
    size_t afb = (size_t)q16*128 + m16*8;           // A-frag base (rows 0..15)

    {   // q-projection
        s8v a[8];
        const unsigned short* ar = rnF + (size_t)g*4096 + afb;
        #pragma unroll
        for (int i = 0; i < 8; ++i) a[i] = *(const s8v*)(ar + i*512);
        f4v acc = {0.f,0.f,0.f,0.f};
        const unsigned short* br = WqTb + fb;
        #pragma unroll
        for (int i = 0; i < 8; ++i){
            s8v bb = *(const s8v*)(br + i*512);
            acc = __builtin_amdgcn_mfma_f32_16x16x32_bf16(a[i], bb, acc, 0, 0, 0);
        }
        #pragma unroll
        for (int r = 0; r < 4; ++r) xc[0][4*q16 + r][n0 + m16] = f2b(acc[r]);
    }
    __syncthreads();

    f4v hacc;
    for (int l = 0; l < 4; ++l){
        s8v xa[8];
        #pragma unroll
        for (int i = 0; i < 8; ++i)
            xa[i] = *(const s8v*)(&xc[l & 1][m16][q16*8 + i*32]);
        const unsigned short* br = WTb + (size_t)l*DDn + fb;
        const unsigned short* bu = ucpb + ((size_t)(b*4 + l)*64 + nl)*65536 + fb;
        f4v acc = {0.f,0.f,0.f,0.f};
        #pragma unroll
        for (int i = 0; i < 8; ++i){
            s8v w0 = *(const s8v*)(br + i*512);
            s8v u0 = *(const s8v*)(bu + i*512);
            acc = __builtin_amdgcn_mfma_f32_16x16x32_bf16(xa[i], w0, acc, 0, 0, 0);
            acc = __builtin_amdgcn_mfma_f32_16x16x32_bf16(xa[i], u0, acc, 0, 0, 0);
        }
        hacc = acc;
        if (l < 3){
            #pragma unroll
            for (int r = 0; r < 4; ++r)
                xc[(l + 1) & 1][4*q16 + r][n0 + m16] = f2b(silu_(hacc[r]));
            __syncthreads();
        }
    }

    // epilogue: post rmsnorm + shift + store
    float part[4];
    #pragma unroll
    for (int r = 0; r < 4; ++r) part[r] = hacc[r]*hacc[r];
    #pragma unroll
    for (int off = 1; off < 16; off <<= 1)
        #pragma unroll
        for (int r = 0; r < 4; ++r) part[r] += __shfl_xor(part[r], off, 64);
    if (m16 == 0)
        #pragma unroll
        for (int r = 0; r < 4; ++r) red[w][4*q16 + r] = part[r];
    __syncthreads();
    if (tid < 16){
        float s = 0.f;
        #pragma unroll
        for (int i = 0; i < 16; ++i) s += red[i][tid];
        rs[tid] = rsqrtf(s*(1.f/256.f) + EPSf);
    }
    __syncthreads();
    {
        int d = n0 + m16;
        float wp = wpost[d];
        #pragma unroll
        for (int r = 0; r < 4; ++r){
            int c = 4*q16 + r;
            int tp = nl*16 + c + 15;
            if (tp < 1024)
                out[((size_t)b*1024 + tp)*256 + d] = hacc[r]*rs[c]*wp;
        }
    }
    if (nl == 0){
        for (int idx = tid; idx < 15*256; idx += 1024)
            out[(size_t)b*262144 + idx] = 0.f;
    }
}

extern "C" void kernel_launch(void* const* d_in, const int* in_sizes, int n_in,
                              void* d_out, int out_size, void* d_ws, size_t ws_size,
                              hipStream_t stream) {
    const float* seq     = (const float*)d_in[0];
    const float* w_store = (const float*)d_in[1];
    const float* w_retr  = (const float*)d_in[2];
    const float* w_post  = (const float*)d_in[3];
    const float* Wq      = (const float*)d_in[4];
    const float* Wkv     = (const float*)d_in[5];
    const float* w_adapt = (const float*)d_in[6];
    const float* w_mom   = (const float*)d_in[7];
    const float* w_decay = (const float*)d_in[8];
    const float* W0      = (const float*)d_in[9];
    const float* W1      = (const float*)d_in[10];
    const float* W2      = (const float*)d_in[11];
    const float* W3      = (const float*)d_in[12];

    float* momg  = (float*)d_ws;                       // 128
    float* decg  = momg + NCn;                         // 128
    unsigned short* snb   = (unsigned short*)(decg + NCn + 32);
    unsigned short* snF   = snb   + (size_t)NCn*4096;
    unsigned short* rnF   = snF   + (size_t)NCn*4096;
    unsigned short* WTb   = rnF   + (size_t)NCn*4096;
    unsigned short* Wb    = WTb   + 4*(size_t)DDn;
    unsigned short* WqTb  = Wb    + 3*(size_t)DDn;
    unsigned short* WkvTb = WqTb  + (size_t)DDn;
    unsigned short* XT    = WkvTb + 2*(size_t)DDn;       // f16 [l][g][d][c], 4 MB
    unsigned short* GT    = XT    + (size_t)4*NCn*4096;  // f16 [l][g][d][c], 4 MB
    unsigned short* ucpb  = GT    + (size_t)4*NCn*4096;  // bf16 frag-order U_g, 67 MB

    ktw   <<<dim3(8, 16, 9),  256,  0, stream>>>(Wq, Wkv, W0, W1, W2, W3,
                                                 WTb, WqTb, WkvTb, Wb);
    knorm <<<dim3(2048),      256,  0, stream>>>(seq, w_store, w_retr, snb, snF, rnF);
    kfb   <<<dim3(NCn),       1024, 0, stream>>>(snb, snF, WkvTb, WTb, Wb,
                                                 w_adapt, w_mom, w_decay,
                                                 momg, decg, XT, GT);
    kck   <<<dim3(16, 16, 8), 64,   0, stream>>>(XT, GT, momg, decg, ucpb);
    kretr <<<dim3(NCn),       1024, 0, stream>>>(rnF, WqTb, WTb, ucpb,
                                                 w_post, (float*)d_out);
}

// Round 13
// 143.322 us; speedup vs baseline: 3.9049x; 1.0268x over previous
//
#include <hip/hip_runtime.h>
#include <hip/hip_bf16.h>

typedef __attribute__((ext_vector_type(8)))  short s8v;   // 8 bf16
typedef __attribute__((ext_vector_type(4)))  float f4v;   // 16x16 C/D
typedef _Float16 h4 __attribute__((ext_vector_type(4)));  // 4 f16
typedef __attribute__((ext_vector_type(4))) unsigned short u4v;

constexpr int NCn  = 128;
constexpr int DDn  = 65536;
constexpr int XP   = 264;             // padded LDS row (bf16 elems)
constexpr float EPSf = 1.1920929e-07f;

__device__ __forceinline__ float sigm(float x){ return 1.0f/(1.0f + expf(-x)); }
__device__ __forceinline__ float silu_(float x){ return x * sigm(x); }
__device__ __forceinline__ float dsilu_(float x){ float s = sigm(x); return s*(1.0f + x*(1.0f - s)); }

__device__ __forceinline__ unsigned short f2b(float x){
    __hip_bfloat16 b = __float2bfloat16(x);
    unsigned short u; __builtin_memcpy(&u, &b, 2); return u;
}
__device__ __forceinline__ float b2f(unsigned short u){
    __hip_bfloat16 b; __builtin_memcpy(&b, &u, 2); return __bfloat162float(b);
}
__device__ __forceinline__ h4 ldh4(const unsigned short* p){
    h4 r; __builtin_memcpy(&r, p, 8); return r;
}

// fragment-order index: element (row, col) of a [R][256] matrix stored so that
// a wave's MFMA fragment load (tile=row>>4, i=col>>5, lane=(q16,m16), j) is a
// contiguous 1KB read:  addr = ((tile*8 + i)*4 + q16)*128 + m16*8 + j
__device__ __forceinline__ int fidx(int row, int col){
    return (((row >> 4)*8 + (col >> 5))*4 + ((col >> 3) & 3))*128 + (row & 15)*8 + (col & 7);
}

// ---- merged weight prep: z 0..5 tiled transpose fp32->bf16 frag-order,
//      z 6..8 cast-copy frag-order ----
__global__ __launch_bounds__(256) void ktw(const float* __restrict__ Wq,
        const float* __restrict__ Wkv, const float* __restrict__ W0,
        const float* __restrict__ W1, const float* __restrict__ W2,
        const float* __restrict__ W3, unsigned short* __restrict__ WTb,
        unsigned short* __restrict__ WqTb, unsigned short* __restrict__ WkvTb,
        unsigned short* __restrict__ Wb){
    int z = blockIdx.z;
    if (z >= 6){
        const float* S = (z==6)?W1:(z==7)?W2:W3;
        size_t idx = (((size_t)blockIdx.y*8 + blockIdx.x)*256 + threadIdx.x)*2;
        float2 v = *(const float2*)(S + idx);
        ushort2 u; u.x = f2b(v.x); u.y = f2b(v.y);
        int row = (int)(idx >> 8), col = (int)(idx & 255);
        *(ushort2*)(Wb + (size_t)(z-6)*DDn + fidx(row, col)) = u;
        return;
    }
    __shared__ float tl[32][33];
    if (z != 5 && blockIdx.y >= 8) return;
    const float* S; unsigned short* T; int C;
    if (z < 4){ S = (z==0)?W0:(z==1)?W1:(z==2)?W2:W3; T = WTb + (size_t)z*DDn; C = 256; }
    else if (z == 4){ S = Wq; T = WqTb; C = 256; }
    else { S = Wkv; T = WkvTb; C = 512; }
    int k0 = blockIdx.x*32, j0 = blockIdx.y*32;
    int tx = threadIdx.x & 31, ty = threadIdx.x >> 5;
    #pragma unroll
    for (int p = 0; p < 4; ++p)
        tl[ty + 8*p][tx] = S[(size_t)(k0 + ty + 8*p)*C + j0 + tx];
    __syncthreads();
    #pragma unroll
    for (int p = 0; p < 4; ++p){
        int r = j0 + ty + 8*p, k = k0 + tx;   // T[r][k] = S[k][r]
        T[fidx(r, k)] = f2b(tl[tx][ty + 8*p]);
    }
}

// ---- fwd + bwd dgrads + fused norm + fused gates, one block per group, 16 waves ----
// sn computed in-block into LDS xs; writes XT f16 [l][g][d][c], GT f16 [l][g][d][c]
__global__ __launch_bounds__(1024, 1) void kfb(const float* __restrict__ seq,
        const float* __restrict__ wsn,
        const unsigned short* __restrict__ WkvTb, const unsigned short* __restrict__ WTb,
        const unsigned short* __restrict__ Wb,
        const float* __restrict__ wa, const float* __restrict__ wm,
        const float* __restrict__ wdk,
        float* __restrict__ momg, float* __restrict__ decg,
        unsigned short* __restrict__ XT, unsigned short* __restrict__ GT){
    __shared__ unsigned short xs[16][XP];
    __shared__ unsigned short xl[4][16][XP];
    __shared__ unsigned short Gs[16][XP];
    __shared__ float red3[16][4];
    int tid = threadIdx.x, w = tid >> 6, lane = tid & 63;
    int m16 = lane & 15, q16 = lane >> 4;
    int g = blockIdx.x;
    int n0 = w*16;
    size_t fb = (size_t)w*4096 + q16*128 + m16*8;   // fragment base for rows n0..n0+15

    {   // in-block store-norm: wave w computes row w of sn
        const float4 xv = *(const float4*)(seq + ((size_t)g*16 + w)*256 + lane*4);
        const float4 wv = *(const float4*)(wsn + lane*4);
        float ssq = xv.x*xv.x + xv.y*xv.y + xv.z*xv.z + xv.w*xv.w;
        #pragma unroll
        for (int off = 32; off; off >>= 1) ssq += __shfl_xor(ssq, off, 64);
        float s2 = rsqrtf(ssq*(1.f/256.f) + EPSf);
        u4v sv;
        sv[0] = f2b(xv.x*s2*wv.x); sv[1] = f2b(xv.y*s2*wv.y);
        sv[2] = f2b(xv.z*s2*wv.z); sv[3] = f2b(xv.w*s2*wv.w);
        *(u4v*)(&xs[w][lane*4]) = sv;
    }
    __syncthreads();

    float sc;
    {   // fused gates: one reduction pass, one barrier (reads xs in LDS)
        int d2 = tid & 255, qt = tid >> 8;
        float a = 0.f;
        #pragma unroll
        for (int c = 0; c < 4; ++c)
            a += b2f(xs[qt*4 + c][d2]);
        float cm = a * (1.f/16.f);
        float s0 = cm*wa[d2], s1 = cm*wm[d2], s2 = cm*wdk[d2];
        #pragma unroll
        for (int off = 32; off; off >>= 1){
            s0 += __shfl_down(s0, off, 64);
            s1 += __shfl_down(s1, off, 64);
            s2 += __shfl_down(s2, off, 64);
        }
        if (lane == 0){ red3[w][0] = s0; red3[w][1] = s1; red3[w][2] = s2; }
        __syncthreads();
        float da = 0.f, dm = 0.f, dc = 0.f;
        #pragma unroll
        for (int i = 0; i < 16; ++i){
            da += red3[i][0]; dm += red3[i][1]; dc += red3[i][2];
        }
        sc = -2.f * sigm(da) * (1.f/256.f);
        if (tid == 0){ momg[g] = sigm(dm); decg[g] = sigm(dc); }
    }

    // A-frags from LDS xs
    s8v af[8];
    #pragma unroll
    for (int i = 0; i < 8; ++i) af[i] = *(const s8v*)(&xs[m16][q16*8 + i*32]);

    // prefetch layer-0 weights (used after next barrier)
    s8v bpre[8];
    #pragma unroll
    for (int i = 0; i < 8; ++i) bpre[i] = *(const s8v*)(WTb + fb + i*512);

    f4v vacc;
    {
        f4v ka = {0.f,0.f,0.f,0.f}, va = {0.f,0.f,0.f,0.f};
        const unsigned short* brK = WkvTb + fb;                 // K rows n0..
        const unsigned short* brV = WkvTb + (size_t)DDn + fb;   // V rows 256+n0..
        #pragma unroll
        for (int i = 0; i < 8; ++i){
            s8v bK = *(const s8v*)(brK + i*512);
            s8v bV = *(const s8v*)(brV + i*512);
            ka = __builtin_amdgcn_mfma_f32_16x16x32_bf16(af[i], bK, ka, 0, 0, 0);
            va = __builtin_amdgcn_mfma_f32_16x16x32_bf16(af[i], bV, va, 0, 0, 0);
        }
        vacc = va;
        #pragma unroll
        for (int r = 0; r < 4; ++r) xl[0][4*q16 + r][n0 + m16] = f2b(ka[r]);
    }

    f4v hreg[3];
    #pragma unroll
    for (int l = 0; l < 3; ++l){
        __syncthreads();
        s8v xa[8];
        #pragma unroll
        for (int i = 0; i < 8; ++i)
            xa[i] = *(const s8v*)(&xl[l][m16][q16*8 + i*32]);
        s8v bcur[8];
        #pragma unroll
        for (int i = 0; i < 8; ++i) bcur[i] = bpre[i];
        const unsigned short* nxt = WTb + (size_t)(l+1)*DDn + fb;
        #pragma unroll
        for (int i = 0; i < 8; ++i) bpre[i] = *(const s8v*)(nxt + i*512);
        f4v acc = {0.f,0.f,0.f,0.f};
        #pragma unroll
        for (int i = 0; i < 8; ++i)
            acc = __builtin_amdgcn_mfma_f32_16x16x32_bf16(xa[i], bcur[i], acc, 0, 0, 0);
        hreg[l] = acc;
        #pragma unroll
        for (int r = 0; r < 4; ++r)
            xl[l+1][4*q16 + r][n0 + m16] = f2b(silu_(acc[r]));
    }
    __syncthreads();

    {   // dump XT f16 [l][g][d][c]
        int d = tid & 255, qt = tid >> 8;
        #pragma unroll
        for (int l = 0; l < 4; ++l){
            h4 v;
            #pragma unroll
            for (int j = 0; j < 4; ++j)
                v[j] = (_Float16)b2f(xl[l][qt*4 + j][d]);
            *(h4*)(XT + (((size_t)l*128 + g)*256 + d)*16 + qt*4) = v;
        }
    }

    {   // layer 3 (pred) -> Gs; prefetch Wb[2] for bwd l=3
        s8v xa[8];
        #pragma unroll
        for (int i = 0; i < 8; ++i)
            xa[i] = *(const s8v*)(&xl[3][m16][q16*8 + i*32]);
        s8v bcur[8];
        #pragma unroll
        for (int i = 0; i < 8; ++i) bcur[i] = bpre[i];
        const unsigned short* nxt = Wb + (size_t)2*DDn + fb;
        #pragma unroll
        for (int i = 0; i < 8; ++i) bpre[i] = *(const s8v*)(nxt + i*512);
        f4v acc = {0.f,0.f,0.f,0.f};
        #pragma unroll
        for (int i = 0; i < 8; ++i)
            acc = __builtin_amdgcn_mfma_f32_16x16x32_bf16(xa[i], bcur[i], acc, 0, 0, 0);
        #pragma unroll
        for (int r = 0; r < 4; ++r)
            Gs[4*q16 + r][n0 + m16] = f2b(sc * (acc[r] - vacc[r]));
    }
    __syncthreads();
    {   // write f16 GT[3][g][d][c]
        int d = tid & 255, qt = tid >> 8;
        h4 v;
        #pragma unroll
        for (int j = 0; j < 4; ++j)
            v[j] = (_Float16)b2f(Gs[qt*4 + j][d]);
        *(h4*)(GT + (((size_t)3*128 + g)*256 + d)*16 + qt*4) = v;
    }

    #pragma unroll
    for (int l = 3; l >= 1; --l){
        s8v gfa[8];
        #pragma unroll
        for (int i = 0; i < 8; ++i)
            gfa[i] = *(const s8v*)(&Gs[m16][q16*8 + i*32]);
        s8v bcur[8];
        #pragma unroll
        for (int i = 0; i < 8; ++i) bcur[i] = bpre[i];
        if (l > 1){
            const unsigned short* nxt = Wb + (size_t)(l-2)*DDn + fb;
            #pragma unroll
            for (int i = 0; i < 8; ++i) bpre[i] = *(const s8v*)(nxt + i*512);
        }
        f4v acc = {0.f,0.f,0.f,0.f};
        #pragma unroll
        for (int i = 0; i < 8; ++i)
            acc = __builtin_amdgcn_mfma_f32_16x16x32_bf16(gfa[i], bcur[i], acc, 0, 0, 0);
        f4v gn;
        #pragma unroll
        for (int r = 0; r < 4; ++r)
            gn[r] = acc[r] * dsilu_(hreg[l-1][r]);
        __syncthreads();
        #pragma unroll
        for (int r = 0; r < 4; ++r)
            Gs[4*q16 + r][n0 + m16] = f2b(gn[r]);
        __syncthreads();
        {
            int d = tid & 255, qt = tid >> 8;
            h4 v;
            #pragma unroll
            for (int j = 0; j < 4; ++j)
                v[j] = (_Float16)b2f(Gs[qt*4 + j][d]);
            *(h4*)(GT + (((size_t)(l-1)*128 + g)*256 + d)*16 + qt*4) = v;
        }
    }
}

// ---- per-chunk update scan -> bf16 U_g checkpoints (frag-order) ----
// grid (16 rowtiles, 16 coltiles, 8 bl), 1 wave/block; exact reference recurrence:
//   S_g = X_g^T G_g ; m = mo_g*m + S_g ; u = (1-dec_g)*u + m ; store u (bf16)
__global__ __launch_bounds__(64, 1) void kck(const unsigned short* __restrict__ XT,
        const unsigned short* __restrict__ GT, const float* __restrict__ momg,
        const float* __restrict__ decg, unsigned short* __restrict__ ucpb){
    int lane = threadIdx.x;
    int m16 = lane & 15, q16 = lane >> 4;
    int rt = blockIdx.x, ct = blockIdx.y, bl = blockIdx.z;
    int b = bl >> 2, l = bl & 3;
    int dr = rt*16 + m16;   // G row (dout)
    int dc = ct*16 + m16;   // X row (din)
    const unsigned short* Gb  = GT + ((size_t)l*128 + b*64)*4096 + (size_t)dr*16 + q16*4;
    const unsigned short* Xb2 = XT + ((size_t)l*128 + b*64)*4096 + (size_t)dc*16 + q16*4;
    // frag-order write base: element (row = rt*16 + 4*q16 + r, col = ct*16 + m16)
    int col = ct*16 + m16;
    int fo0 = ((rt*8 + (col >> 5))*4 + ((col >> 3) & 3))*128 + (4*q16)*8 + (col & 7);
    f4v us = {0.f,0.f,0.f,0.f}, ms = {0.f,0.f,0.f,0.f};
    #pragma unroll 4
    for (int n = 0; n < 64; ++n){
        float mo = momg[b*64 + n], de = 1.f - decg[b*64 + n];
        h4 a  = ldh4(Gb  + (size_t)n*4096);
        h4 xb = ldh4(Xb2 + (size_t)n*4096);
        f4v z = {0.f,0.f,0.f,0.f};
        f4v s = __builtin_amdgcn_mfma_f32_16x16x16f16(a, xb, z, 0, 0, 0);
        size_t cb = ((size_t)bl*64 + n)*65536;
        #pragma unroll
        for (int r = 0; r < 4; ++r){
            float mn = mo*ms[r] + s[r];
            float un = de*us[r] + mn;
            ms[r] = mn; us[r] = un;
            ucpb[cb + fo0 + r*8] = f2b(un);
        }
    }
}

// ---- retrieval: fused retrieve-norm + q-proj + 4 layers { x @ (W_l + U_g) } ----
// 16 waves; all fragment loads contiguous 1KB/wave; 1 barrier/layer
__global__ __launch_bounds__(1024, 1) void kretr(const float* __restrict__ seq,
        const float* __restrict__ wrn,
        const unsigned short* __restrict__ WqTb, const unsigned short* __restrict__ WTb,
        const unsigned short* __restrict__ ucpb, const float* __restrict__ wpost,
        float* __restrict__ out){
    __shared__ unsigned short xc[2][16][XP];
    __shared__ float red[16][16];
    __shared__ float rs[16];
    int tid = threadIdx.x, w = tid >> 6, lane = tid & 63;
    int m16 = lane & 15, q16 = lane >> 4;
    int g = blockIdx.x;
    int b = g >> 6, nl = g & 63;
    int n0 = w*16;
    size_t fb = (size_t)w*4096 + q16*128 + m16*8;   // fragment base (rows n0..n0+15)

    {   // in-block retrieve-norm (shifted): wave w computes row w (token p+15)
        int p = nl*16 + w + 15;
        u4v sv = {0,0,0,0};
        if (p < 1024){
            const float4 xv = *(const float4*)(seq + ((size_t)b*1024 + p)*256 + lane*4);
            const float4 wv = *(const float4*)(wrn + lane*4);
            float ssq = xv.x*xv.x + xv.y*xv.y + xv.z*xv.z + xv.w*xv.w;
            #pragma unroll
            for (int off = 32; off; off >>= 1) ssq += __shfl_xor(ssq, off, 64);
            float s2 = rsqrtf(ssq*(1.f/256.f) + EPSf);
            sv[0] = f2b(xv.x*s2*wv.x); sv[1] = f2b(xv.y*s2*wv.y);
            sv[2] = f2b(xv.z*s2*wv.z); sv[3] = f2b(xv.w*s2*wv.w);
        }
        *(u4v*)(&xc[1][w][lane*4]) = sv;
    }
    __syncthreads();

    {   // q-projection (reads rn from xc[1], writes xc[0])
        s8v a[8];
        #pragma unroll
        for (int i = 0; i < 8; ++i) a[i] = *(const s8v*)(&xc[1][m16][q16*8 + i*32]);
        f4v acc = {0.f,0.f,0.f,0.f};
        const unsigned short* br = WqTb + fb;
        #pragma unroll
        for (int i = 0; i < 8; ++i){
            s8v bb = *(const s8v*)(br + i*512);
            acc = __builtin_amdgcn_mfma_f32_16x16x32_bf16(a[i], bb, acc, 0, 0, 0);
        }
        #pragma unroll
        for (int r = 0; r < 4; ++r) xc[0][4*q16 + r][n0 + m16] = f2b(acc[r]);
    }
    __syncthreads();

    f4v hacc;
    for (int l = 0; l < 4; ++l){
        s8v xa[8];
        #pragma unroll
        for (int i = 0; i < 8; ++i)
            xa[i] = *(const s8v*)(&xc[l & 1][m16][q16*8 + i*32]);
        const unsigned short* br = WTb + (size_t)l*DDn + fb;
        const unsigned short* bu = ucpb + ((size_t)(b*4 + l)*64 + nl)*65536 + fb;
        f4v aW = {0.f,0.f,0.f,0.f}, aU = {0.f,0.f,0.f,0.f};
        #pragma unroll
        for (int i = 0; i < 8; ++i){
            s8v w0 = *(const s8v*)(br + i*512);
            s8v u0 = *(const s8v*)(bu + i*512);
            aW = __builtin_amdgcn_mfma_f32_16x16x32_bf16(xa[i], w0, aW, 0, 0, 0);
            aU = __builtin_amdgcn_mfma_f32_16x16x32_bf16(xa[i], u0, aU, 0, 0, 0);
        }
        #pragma unroll
        for (int r = 0; r < 4; ++r) hacc[r] = aW[r] + aU[r];
        if (l < 3){
            #pragma unroll
            for (int r = 0; r < 4; ++r)
                xc[(l + 1) & 1][4*q16 + r][n0 + m16] = f2b(silu_(hacc[r]));
            __syncthreads();
        }
    }

    // epilogue: post rmsnorm + shift + store
    float part[4];
    #pragma unroll
    for (int r = 0; r < 4; ++r) part[r] = hacc[r]*hacc[r];
    #pragma unroll
    for (int off = 1; off < 16; off <<= 1)
        #pragma unroll
        for (int r = 0; r < 4; ++r) part[r] += __shfl_xor(part[r], off, 64);
    if (m16 == 0)
        #pragma unroll
        for (int r = 0; r < 4; ++r) red[w][4*q16 + r] = part[r];
    __syncthreads();
    if (tid < 16){
        float s = 0.f;
        #pragma unroll
        for (int i = 0; i < 16; ++i) s += red[i][tid];
        rs[tid] = rsqrtf(s*(1.f/256.f) + EPSf);
    }
    __syncthreads();
    {
        int d = n0 + m16;
        float wp = wpost[d];
        #pragma unroll
        for (int r = 0; r < 4; ++r){
            int c = 4*q16 + r;
            int tp = nl*16 + c + 15;
            if (tp < 1024)
                out[((size_t)b*1024 + tp)*256 + d] = hacc[r]*rs[c]*wp;
        }
    }
    if (nl == 0){
        for (int idx = tid; idx < 15*256; idx += 1024)
            out[(size_t)b*262144 + idx] = 0.f;
    }
}

extern "C" void kernel_launch(void* const* d_in, const int* in_sizes, int n_in,
                              void* d_out, int out_size, void* d_ws, size_t ws_size,
                              hipStream_t stream) {
    const float* seq     = (const float*)d_in[0];
    const float* w_store = (const float*)d_in[1];
    const float* w_retr  = (const float*)d_in[2];
    const float* w_post  = (const float*)d_in[3];
    const float* Wq      = (const float*)d_in[4];
    const float* Wkv     = (const float*)d_in[5];
    const float* w_adapt = (const float*)d_in[6];
    const float* w_mom   = (const float*)d_in[7];
    const float* w_decay = (const float*)d_in[8];
    const float* W0      = (const float*)d_in[9];
    const float* W1      = (const float*)d_in[10];
    const float* W2      = (const float*)d_in[11];
    const float* W3      = (const float*)d_in[12];

    float* momg  = (float*)d_ws;                       // 128
    float* decg  = momg + NCn;                         // 128
    unsigned short* WTb   = (unsigned short*)(decg + NCn + 32);
    unsigned short* Wb    = WTb   + 4*(size_t)DDn;
    unsigned short* WqTb  = Wb    + 3*(size_t)DDn;
    unsigned short* WkvTb = WqTb  + (size_t)DDn;
    unsigned short* XT    = WkvTb + 2*(size_t)DDn;       // f16 [l][g][d][c], 4 MB
    unsigned short* GT    = XT    + (size_t)4*NCn*4096;  // f16 [l][g][d][c], 4 MB
    unsigned short* ucpb  = GT    + (size_t)4*NCn*4096;  // bf16 frag-order U_g, 67 MB

    ktw   <<<dim3(8, 16, 9),  256,  0, stream>>>(Wq, Wkv, W0, W1, W2, W3,
                                                 WTb, WqTb, WkvTb, Wb);
    kfb   <<<dim3(NCn),       1024, 0, stream>>>(seq, w_store, WkvTb, WTb, Wb,
                                                 w_adapt, w_mom, w_decay,
                                                 momg, decg, XT, GT);
    kck   <<<dim3(16, 16, 8), 64,   0, stream>>>(XT, GT, momg, decg, ucpb);
    kretr <<<dim3(NCn),       1024, 0, stream>>>(seq, w_retr, WqTb, WTb, ucpb,
                                                 w_post, (float*)d_out);
}